// Round 1
// baseline (2136.204 us; speedup 1.0000x reference)
//
#include <hip/hip_runtime.h>
#include <math.h>

// Fbank: frame -> DC-remove -> preemph -> Hamming -> 512-pt DFT (brute force)
// -> power -> mel(80) -> log.   B=32, T=480000, 2998 frames/batch.
// Key fact: mel_weight[:,256] == 0 (zero pad), so bin 256 is dead -> 256 bins.

#define BATCH 32
#define TLEN 480000
#define NFRAMES 2998            // (480000-400)/160 + 1
#define FL 400                  // frame length
#define FS 160                  // frame shift
#define PW 512                  // padded window
#define NB 256                  // effective FFT bins (bin 256 has zero mel weight)
#define NM 80                   // mel bins
#define TF 16                   // frames per block
#define PRE 0.97f
#define EPSF 1e-6f

__global__ __launch_bounds__(256, 3) void fbank_kernel(
    const float* __restrict__ wave,     // [32][480000]
    const float* __restrict__ win,      // [400]
    const float* __restrict__ dftr,     // [257][512]
    const float* __restrict__ dfti,     // [257][512]
    const float* __restrict__ melw,     // [80][257]
    float* __restrict__ out)            // [32][2998][80]
{
    __shared__ float s_fr[TF][PW];      // 32 KB processed frames
    __shared__ float s_pw[TF][NB + 1];  // 16.4 KB power spectrum (+1 pad)

    const int tid  = threadIdx.x;
    const int wv   = tid >> 6;          // wave id 0..3
    const int lane = tid & 63;
    const int fbase = blockIdx.x * TF;  // first global frame of this block

    // ---------------- Phase 1: preprocess (4 frames per wave) ----------------
    #pragma unroll
    for (int j = 0; j < TF / 4; ++j) {
        const int lf  = wv * (TF / 4) + j;
        const int gid = fbase + lf;
        const int bb  = gid / NFRAMES;
        const int fr  = gid - bb * NFRAMES;
        const float* x = wave + (size_t)bb * TLEN + (size_t)fr * FS;

        // mean over 400 samples: per-lane partial + 64-lane butterfly reduce
        float s = 0.f;
        for (int i = lane; i < FL; i += 64) s += x[i];
        #pragma unroll
        for (int off = 32; off >= 1; off >>= 1) s += __shfl_xor(s, off);
        const float mean = s * (1.0f / FL);

        // preemphasis on DC-removed signal: y[i] = d[i] - 0.97*d[i-1],
        // d = x - mean, d[-1] := d[0]  =>  y[i] = x[i] - .97*x[i-1] - .03*mean
        for (int i = lane; i < FL; i += 64) {
            const float xi = x[i];
            const float xm = (i == 0) ? xi : x[i - 1];
            const float y  = xi - PRE * xm - (1.0f - PRE) * mean;
            s_fr[lf][i] = y * win[i];
        }
        for (int i = FL + lane; i < PW; i += 64) s_fr[lf][i] = 0.f;
    }
    __syncthreads();

    // ---------------- Phase 2: DFT + power (thread t == bin t) ----------------
    {
        const int bin = tid;            // 256 threads, 256 live bins
        const float4* __restrict__ dr4 = (const float4*)(dftr + (size_t)bin * PW);
        const float4* __restrict__ di4 = (const float4*)(dfti + (size_t)bin * PW);

        float accr[TF], acci[TF];
        #pragma unroll
        for (int f = 0; f < TF; ++f) { accr[f] = 0.f; acci[f] = 0.f; }

        for (int k4 = 0; k4 < PW / 4; ++k4) {
            const float4 r  = dr4[k4];
            const float4 im = di4[k4];
            #pragma unroll
            for (int f = 0; f < TF; ++f) {
                const float4 fr = *(const float4*)&s_fr[f][k4 * 4];  // LDS broadcast
                accr[f] += fr.x * r.x  + fr.y * r.y  + fr.z * r.z  + fr.w * r.w;
                acci[f] += fr.x * im.x + fr.y * im.y + fr.z * im.z + fr.w * im.w;
            }
        }
        #pragma unroll
        for (int f = 0; f < TF; ++f)
            s_pw[f][bin] = accr[f] * accr[f] + acci[f] * acci[f];
    }
    __syncthreads();

    // ---------------- Phase 3: mel projection + log ----------------
    for (int o = tid; o < TF * NM; o += 256) {
        const int f = o / NM;
        const int m = o - f * NM;
        const float* __restrict__ w = melw + (size_t)m * 257;  // col 256 unused (==0)
        float acc = 0.f;
        for (int k = 0; k < NB; ++k)
            acc += s_pw[f][k] * w[k];
        acc += EPSF;
        acc = fmaxf(acc, EPSF);
        const int gid = fbase + f;
        out[(size_t)gid * NM + m] = logf(acc);
    }
}

extern "C" void kernel_launch(void* const* d_in, const int* in_sizes, int n_in,
                              void* d_out, int out_size, void* d_ws, size_t ws_size,
                              hipStream_t stream) {
    const float* wave = (const float*)d_in[0];
    const float* win  = (const float*)d_in[1];
    const float* dftr = (const float*)d_in[2];
    const float* dfti = (const float*)d_in[3];
    const float* melw = (const float*)d_in[4];
    float* out = (float*)d_out;

    const int nblocks = (BATCH * NFRAMES) / TF;   // 95936/16 = 5996 exactly
    fbank_kernel<<<nblocks, 256, 0, stream>>>(wave, win, dftr, dfti, melw, out);
}

// Round 3
// 250.483 us; speedup vs baseline: 8.5283x; 8.5283x over previous
//
#include <hip/hip_runtime.h>
#include <math.h>

// Fbank via split-bf16 MFMA: preprocess -> hi/lo bf16 A-tiles in LDS (XOR-swizzled)
// -> DFT GEMM with 3-term split product (AhBh + AlBh + AhBl) for fp32-ish precision
// -> power (bf16, no cancellation -> safe) -> mel GEMM (MFMA) -> log.
// mel_weight[:,256]==0 so only 256 bins live; frame zero beyond k=400 -> K_eff=416.

#define BATCH 32
#define TLEN 480000
#define NFRAMES 2998
#define FL 400
#define FS 160
#define PW 512
#define NM 80
#define MT 32                // frames per block
#define NTILES 94            // ceil(2998/32)
#define KS_MAIN 13           // k-steps of 32: covers k<416 (A is zero for k>=400)
#define PRE 0.97f
#define EPSF 1e-6f

typedef short bf16x8 __attribute__((ext_vector_type(8)));
typedef float f32x4 __attribute__((ext_vector_type(4)));
typedef unsigned int u32;
typedef unsigned short u16;

#define MAIN_GROUPS (32 * KS_MAIN * 64)   // 26624 fragment-groups (re+im x 13 ks)
#define MAIN_U16 (MAIN_GROUPS * 8)        // 212992 u16 per plane (hi, lo)
#define MEL_GROUPS (6 * 8 * 64)           // 3072
#define MEL_U16 (MEL_GROUPS * 8)
#define WS_NEED ((size_t)(2 * MAIN_U16 + MEL_U16) * 2)   // ~901 KB

__device__ __forceinline__ u16 f2bf(float f) {
    u32 u = __builtin_bit_cast(u32, f);
    return (u16)((u + 0x7FFFu + ((u >> 16) & 1u)) >> 16);
}
__device__ __forceinline__ float bf2f(u16 h) {
    u32 u = ((u32)h) << 16;
    return __builtin_bit_cast(float, u);
}

// ---------------- prep: pack B (DFT re/im, hi+lo planes) + mel weights ----------------
__global__ void prep_kernel(const float* __restrict__ dftr, const float* __restrict__ dfti,
                            const float* __restrict__ melw, u16* __restrict__ wsb) {
    int idx = blockIdx.x * 256 + threadIdx.x;
    if (idx < MAIN_GROUPS) {
        int nf = idx / (KS_MAIN * 64);
        int rem = idx - nf * (KS_MAIN * 64);
        int ks = rem >> 6;
        int l  = rem & 63;
        int n  = nf * 16 + (l & 15);          // 0..511: re 0..255, im 256..511
        int k  = ks * 32 + ((l >> 4) << 3);   // < 416 <= 512
        const float* src = (n < 256) ? (dftr + (size_t)n * PW + k)
                                     : (dfti + (size_t)(n - 256) * PW + k);
        u16* dh = wsb + (size_t)idx * 8;
        u16* dl = wsb + (size_t)MAIN_U16 + (size_t)idx * 8;
        #pragma unroll
        for (int e = 0; e < 8; ++e) {
            float x = src[e];
            u16 h = f2bf(x);
            dh[e] = h;
            dl[e] = f2bf(x - bf2f(h));
        }
    } else {
        int j = idx - MAIN_GROUPS;
        if (j < MEL_GROUPS) {
            int nf = j / (8 * 64);
            int ks = (j >> 6) & 7;
            int l  = j & 63;
            int n  = nf * 16 + (l & 15);
            int k  = ks * 32 + ((l >> 4) << 3);
            u16* dst = wsb + (size_t)(2 * MAIN_U16) + (size_t)j * 8;
            if (n < NM) {
                const float* src = melw + (size_t)n * 257 + k;   // col 256 never read
                #pragma unroll
                for (int e = 0; e < 8; ++e) dst[e] = f2bf(src[e]);
            } else {
                #pragma unroll
                for (int e = 0; e < 8; ++e) dst[e] = 0;          // pad frags (n 80..95)
            }
        }
    }
}

// ---------------- main fused kernel ----------------
__global__ __launch_bounds__(256) void fbank_mfma(
    const float* __restrict__ wave, const float* __restrict__ win,
    const u16* __restrict__ wsb, float* __restrict__ out) {
    __shared__ u16 sAh[MT * PW];       // 32 KB hi plane (power overlays it later)
    __shared__ u16 sAl[MT * PW];       // 32 KB lo plane

    const int tid = threadIdx.x, w = tid >> 6, lane = tid & 63;
    const int b = blockIdx.y;
    const int f0 = blockIdx.x * MT;
    const float* wb = wave + (size_t)b * TLEN;

    // ---- Phase 1: preprocess 8 frames per wave into swizzled hi/lo bf16 A ----
    for (int q = 0; q < 8; ++q) {
        const int rr = w * 8 + q;
        const int fr = f0 + rr;
        const bool valid = fr < NFRAMES;
        const float* x = wb + (size_t)fr * FS;
        float mean = 0.f;
        if (valid) {
            float s = 0.f;
            for (int i = lane; i < FL; i += 64) s += x[i];
            #pragma unroll
            for (int o = 32; o; o >>= 1) s += __shfl_xor(s, o);
            mean = s * (1.0f / FL);
        }
        #pragma unroll
        for (int t = 0; t < 4; ++t) {
            const int p = lane + 64 * t;     // bf16 pair index 0..255
            const int i0 = p * 2;
            float y0 = 0.f, y1 = 0.f;
            if (valid && i0 < FL) {
                float xm1 = (i0 == 0) ? x[0] : x[i0 - 1];
                float x0 = x[i0], x1 = x[i0 + 1];
                y0 = (x0 - PRE * xm1 - (1.f - PRE) * mean) * win[i0];
                y1 = (x1 - PRE * x0  - (1.f - PRE) * mean) * win[i0 + 1];
            }
            u16 h0 = f2bf(y0), h1 = f2bf(y1);
            u16 l0 = f2bf(y0 - bf2f(h0)), l1 = f2bf(y1 - bf2f(h1));
            u32 byte = (u32)rr * 1024u + (u32)p * 4u;
            byte ^= (u32)(rr & 7) << 4;      // T2 swizzle
            *(u32*)((char*)sAh + byte) = (u32)h0 | ((u32)h1 << 16);
            *(u32*)((char*)sAl + byte) = (u32)l0 | ((u32)l1 << 16);
        }
    }
    __syncthreads();

    // ---- Phase 2: DFT GEMM, wave g owns bins 64g..64g+63, 3-term split product ----
    const int g = w;
    f32x4 accR[2][4], accI[2][4];
    #pragma unroll
    for (int mf = 0; mf < 2; ++mf)
        #pragma unroll
        for (int j = 0; j < 4; ++j) { accR[mf][j] = (f32x4)0.f; accI[mf][j] = (f32x4)0.f; }

    const u16* bh = wsb;
    const u16* bl = wsb + MAIN_U16;

    for (int ks = 0; ks < KS_MAIN; ++ks) {
        bf16x8 aH[2], aL[2];
        #pragma unroll
        for (int mf = 0; mf < 2; ++mf) {
            u32 row = (u32)(mf * 16 + (lane & 15));
            u32 byte = row * 1024u + (u32)(ks * 32 + ((lane >> 4) << 3)) * 2u;
            byte ^= (row & 7) << 4;
            aH[mf] = *(const bf16x8*)((const char*)sAh + byte);
            aL[mf] = *(const bf16x8*)((const char*)sAl + byte);
        }
        #pragma unroll
        for (int j = 0; j < 4; ++j) {
            const int nfR = 4 * g + j, nfI = 16 + 4 * g + j;
            const size_t oR = ((size_t)(nfR * KS_MAIN + ks) * 64 + lane) * 8;
            const size_t oI = ((size_t)(nfI * KS_MAIN + ks) * 64 + lane) * 8;
            bf16x8 bRh = *(const bf16x8*)(bh + oR);
            bf16x8 bRl = *(const bf16x8*)(bl + oR);
            bf16x8 bIh = *(const bf16x8*)(bh + oI);
            bf16x8 bIl = *(const bf16x8*)(bl + oI);
            #pragma unroll
            for (int mf = 0; mf < 2; ++mf) {
                accR[mf][j] = __builtin_amdgcn_mfma_f32_16x16x32_bf16(aH[mf], bRh, accR[mf][j], 0, 0, 0);
                accR[mf][j] = __builtin_amdgcn_mfma_f32_16x16x32_bf16(aL[mf], bRh, accR[mf][j], 0, 0, 0);
                accR[mf][j] = __builtin_amdgcn_mfma_f32_16x16x32_bf16(aH[mf], bRl, accR[mf][j], 0, 0, 0);
                accI[mf][j] = __builtin_amdgcn_mfma_f32_16x16x32_bf16(aH[mf], bIh, accI[mf][j], 0, 0, 0);
                accI[mf][j] = __builtin_amdgcn_mfma_f32_16x16x32_bf16(aL[mf], bIh, accI[mf][j], 0, 0, 0);
                accI[mf][j] = __builtin_amdgcn_mfma_f32_16x16x32_bf16(aH[mf], bIl, accI[mf][j], 0, 0, 0);
            }
        }
    }
    __syncthreads();   // all A reads done before overlay

    // ---- Phase 3: power -> LDS bf16 [32][256] overlaying sAh, swizzled ----
    #pragma unroll
    for (int mf = 0; mf < 2; ++mf)
        #pragma unroll
        for (int j = 0; j < 4; ++j)
            #pragma unroll
            for (int r = 0; r < 4; ++r) {
                float pR = accR[mf][j][r], pI = accI[mf][j][r];
                float pw = pR * pR + pI * pI;
                u32 row = (u32)(mf * 16 + ((lane >> 4) << 2) + r);
                u32 bin = (u32)(64 * g + j * 16 + (lane & 15));
                u32 byte = row * 512u + bin * 2u;
                byte ^= (row & 7) << 4;
                *(u16*)((char*)sAh + byte) = f2bf(pw);
            }
    __syncthreads();

    // ---- Phase 4: mel GEMM (M=32, N=96 padded, K=256) + log epilogue ----
    const int mfm = w >> 1;            // rows mfm*16..+15
    const int nf0 = (w & 1) ? 3 : 0;   // frag trio {0,1,2} or {3,4,5(pad)}
    f32x4 accM[3];
    #pragma unroll
    for (int j = 0; j < 3; ++j) accM[j] = (f32x4)0.f;

    const u16* melb = wsb + (size_t)(2 * MAIN_U16);
    for (int ks = 0; ks < 8; ++ks) {
        u32 row = (u32)(mfm * 16 + (lane & 15));
        u32 byte = row * 512u + (u32)(ks * 32 + ((lane >> 4) << 3)) * 2u;
        byte ^= (row & 7) << 4;
        bf16x8 aP = *(const bf16x8*)((const char*)sAh + byte);
        #pragma unroll
        for (int j = 0; j < 3; ++j) {
            bf16x8 bM = *(const bf16x8*)(melb + ((size_t)((nf0 + j) * 8 + ks) * 64 + lane) * 8);
            accM[j] = __builtin_amdgcn_mfma_f32_16x16x32_bf16(aP, bM, accM[j], 0, 0, 0);
        }
    }
    #pragma unroll
    for (int j = 0; j < 3; ++j) {
        const int m = (nf0 + j) * 16 + (lane & 15);
        #pragma unroll
        for (int r = 0; r < 4; ++r) {
            const int rowl = mfm * 16 + ((lane >> 4) << 2) + r;
            const int fr = f0 + rowl;
            if (fr < NFRAMES && m < NM) {
                float v = fmaxf(accM[j][r] + EPSF, EPSF);
                out[((size_t)b * NFRAMES + fr) * NM + m] = logf(v);
            }
        }
    }
}

// ---------------- fallback (round-1 fp32 kernel, used if ws too small) ----------------
#define TFB 16
#define NB 256
__global__ __launch_bounds__(256, 3) void fbank_fallback(
    const float* __restrict__ wave, const float* __restrict__ win,
    const float* __restrict__ dftr, const float* __restrict__ dfti,
    const float* __restrict__ melw, float* __restrict__ out) {
    __shared__ float s_fr[TFB][PW];
    __shared__ float s_pw[TFB][NB + 1];
    const int tid = threadIdx.x, wv = tid >> 6, lane = tid & 63;
    const int fbase = blockIdx.x * TFB;
    #pragma unroll
    for (int j = 0; j < TFB / 4; ++j) {
        const int lf = wv * (TFB / 4) + j;
        const int gid = fbase + lf;
        const int bb = gid / NFRAMES;
        const int fr = gid - bb * NFRAMES;
        const float* x = wave + (size_t)bb * TLEN + (size_t)fr * FS;
        float s = 0.f;
        for (int i = lane; i < FL; i += 64) s += x[i];
        #pragma unroll
        for (int off = 32; off >= 1; off >>= 1) s += __shfl_xor(s, off);
        const float mean = s * (1.0f / FL);
        for (int i = lane; i < FL; i += 64) {
            const float xi = x[i];
            const float xm = (i == 0) ? xi : x[i - 1];
            s_fr[lf][i] = (xi - PRE * xm - (1.0f - PRE) * mean) * win[i];
        }
        for (int i = FL + lane; i < PW; i += 64) s_fr[lf][i] = 0.f;
    }
    __syncthreads();
    {
        const int bin = tid;
        const float4* dr4 = (const float4*)(dftr + (size_t)bin * PW);
        const float4* di4 = (const float4*)(dfti + (size_t)bin * PW);
        float accr[TFB], acci[TFB];
        #pragma unroll
        for (int f = 0; f < TFB; ++f) { accr[f] = 0.f; acci[f] = 0.f; }
        for (int k4 = 0; k4 < PW / 4; ++k4) {
            const float4 r = dr4[k4], im = di4[k4];
            #pragma unroll
            for (int f = 0; f < TFB; ++f) {
                const float4 fr = *(const float4*)&s_fr[f][k4 * 4];
                accr[f] += fr.x * r.x + fr.y * r.y + fr.z * r.z + fr.w * r.w;
                acci[f] += fr.x * im.x + fr.y * im.y + fr.z * im.z + fr.w * im.w;
            }
        }
        #pragma unroll
        for (int f = 0; f < TFB; ++f) s_pw[f][bin] = accr[f] * accr[f] + acci[f] * acci[f];
    }
    __syncthreads();
    for (int o = tid; o < TFB * NM; o += 256) {
        const int f = o / NM, m = o - f * NM;
        const float* wm = melw + (size_t)m * 257;
        float acc = 0.f;
        for (int k = 0; k < NB; ++k) acc += s_pw[f][k] * wm[k];
        out[(size_t)(fbase + f) * NM + m] = logf(fmaxf(acc + EPSF, EPSF));
    }
}

extern "C" void kernel_launch(void* const* d_in, const int* in_sizes, int n_in,
                              void* d_out, int out_size, void* d_ws, size_t ws_size,
                              hipStream_t stream) {
    const float* wave = (const float*)d_in[0];
    const float* win  = (const float*)d_in[1];
    const float* dftr = (const float*)d_in[2];
    const float* dfti = (const float*)d_in[3];
    const float* melw = (const float*)d_in[4];
    float* out = (float*)d_out;

    if (ws_size >= WS_NEED) {
        u16* wsb = (u16*)d_ws;
        const int prep_threads = MAIN_GROUPS + MEL_GROUPS;
        prep_kernel<<<(prep_threads + 255) / 256, 256, 0, stream>>>(dftr, dfti, melw, wsb);
        dim3 grid(NTILES, BATCH);
        fbank_mfma<<<grid, 256, 0, stream>>>(wave, win, wsb, out);
    } else {
        const int nblocks = (BATCH * NFRAMES) / TFB;
        fbank_fallback<<<nblocks, 256, 0, stream>>>(wave, win, dftr, dfti, melw, out);
    }
}

// Round 4
// 207.561 us; speedup vs baseline: 10.2919x; 1.2068x over previous
//
#include <hip/hip_runtime.h>
#include <math.h>

// Fbank via split-bf16 MFMA. R4: A-planes stored at 832-B row stride (k<416 only)
// -> LDS 52 KB -> 3 blocks/CU (was 2); swizzle ((row>>1)&3)<<4 for the 832 stride;
// software-pipelined A (ds_read) and B (global) fragment prefetch.

#define BATCH 32
#define TLEN 480000
#define NFRAMES 2998
#define FL 400
#define FS 160
#define PW 512
#define NM 80
#define MT 32                // frames per block
#define NTILES 94            // ceil(2998/32)
#define KS_MAIN 13           // k-steps of 32: covers k<416 (A zero for k>=400)
#define AROW 832             // bytes per A row in LDS (416 bf16)
#define PRE 0.97f
#define EPSF 1e-6f

typedef short bf16x8 __attribute__((ext_vector_type(8)));
typedef float f32x4 __attribute__((ext_vector_type(4)));
typedef unsigned int u32;
typedef unsigned short u16;

#define MAIN_GROUPS (32 * KS_MAIN * 64)   // 26624 fragment-groups (re+im x 13 ks)
#define MAIN_U16 (MAIN_GROUPS * 8)        // 212992 u16 per plane (hi, lo)
#define MEL_GROUPS (6 * 8 * 64)           // 3072
#define MEL_U16 (MEL_GROUPS * 8)
#define WS_NEED ((size_t)(2 * MAIN_U16 + MEL_U16) * 2)   // ~901 KB

__device__ __forceinline__ u16 f2bf(float f) {
    u32 u = __builtin_bit_cast(u32, f);
    return (u16)((u + 0x7FFFu + ((u >> 16) & 1u)) >> 16);
}
__device__ __forceinline__ float bf2f(u16 h) {
    u32 u = ((u32)h) << 16;
    return __builtin_bit_cast(float, u);
}

// ---------------- prep: pack B (DFT re/im, hi+lo planes) + mel weights ----------------
__global__ void prep_kernel(const float* __restrict__ dftr, const float* __restrict__ dfti,
                            const float* __restrict__ melw, u16* __restrict__ wsb) {
    int idx = blockIdx.x * 256 + threadIdx.x;
    if (idx < MAIN_GROUPS) {
        int nf = idx / (KS_MAIN * 64);
        int rem = idx - nf * (KS_MAIN * 64);
        int ks = rem >> 6;
        int l  = rem & 63;
        int n  = nf * 16 + (l & 15);          // 0..511: re 0..255, im 256..511
        int k  = ks * 32 + ((l >> 4) << 3);   // < 416 <= 512
        const float* src = (n < 256) ? (dftr + (size_t)n * PW + k)
                                     : (dfti + (size_t)(n - 256) * PW + k);
        u16* dh = wsb + (size_t)idx * 8;
        u16* dl = wsb + (size_t)MAIN_U16 + (size_t)idx * 8;
        #pragma unroll
        for (int e = 0; e < 8; ++e) {
            float x = src[e];
            u16 h = f2bf(x);
            dh[e] = h;
            dl[e] = f2bf(x - bf2f(h));
        }
    } else {
        int j = idx - MAIN_GROUPS;
        if (j < MEL_GROUPS) {
            int nf = j / (8 * 64);
            int ks = (j >> 6) & 7;
            int l  = j & 63;
            int n  = nf * 16 + (l & 15);
            int k  = ks * 32 + ((l >> 4) << 3);
            u16* dst = wsb + (size_t)(2 * MAIN_U16) + (size_t)j * 8;
            if (n < NM) {
                const float* src = melw + (size_t)n * 257 + k;   // col 256 never read
                #pragma unroll
                for (int e = 0; e < 8; ++e) dst[e] = f2bf(src[e]);
            } else {
                #pragma unroll
                for (int e = 0; e < 8; ++e) dst[e] = 0;          // pad frags (n 80..95)
            }
        }
    }
}

// A-plane swizzle for 832-B stride: spreads rows across 4-bank groups
#define SWA(row) ((((u32)(row) >> 1) & 3u) << 4)

// ---------------- main fused kernel ----------------
__global__ __launch_bounds__(256, 3) void fbank_mfma(
    const float* __restrict__ wave, const float* __restrict__ win,
    const u16* __restrict__ wsb, float* __restrict__ out) {
    __shared__ u16 sAh[MT * 416];      // 26 KB hi plane (power overlays it later)
    __shared__ u16 sAl[MT * 416];      // 26 KB lo plane

    const int tid = threadIdx.x, w = tid >> 6, lane = tid & 63;
    const int b = blockIdx.y;
    const int f0 = blockIdx.x * MT;
    const float* wb = wave + (size_t)b * TLEN;

    // ---- Phase 1: preprocess 8 frames per wave into swizzled hi/lo bf16 A ----
    for (int q = 0; q < 8; ++q) {
        const int rr = w * 8 + q;
        const int fr = f0 + rr;
        const bool valid = fr < NFRAMES;
        const float* x = wb + (size_t)fr * FS;
        float mean = 0.f;
        if (valid) {
            float s = 0.f;
            for (int i = lane; i < FL; i += 64) s += x[i];
            #pragma unroll
            for (int o = 32; o; o >>= 1) s += __shfl_xor(s, o);
            mean = s * (1.0f / FL);
        }
        #pragma unroll
        for (int t = 0; t < 4; ++t) {
            const int p = lane + 64 * t;     // bf16 pair index 0..207
            if (p < 208) {
                const int i0 = p * 2;
                float y0 = 0.f, y1 = 0.f;
                if (valid && i0 < FL) {
                    float xm1 = (i0 == 0) ? x[0] : x[i0 - 1];
                    float x0 = x[i0], x1 = x[i0 + 1];
                    y0 = (x0 - PRE * xm1 - (1.f - PRE) * mean) * win[i0];
                    y1 = (x1 - PRE * x0  - (1.f - PRE) * mean) * win[i0 + 1];
                }
                u16 h0 = f2bf(y0), h1 = f2bf(y1);
                u16 l0 = f2bf(y0 - bf2f(h0)), l1 = f2bf(y1 - bf2f(h1));
                u32 byte = (u32)rr * AROW + (((u32)p * 4u) ^ SWA(rr));
                *(u32*)((char*)sAh + byte) = (u32)h0 | ((u32)h1 << 16);
                *(u32*)((char*)sAl + byte) = (u32)l0 | ((u32)l1 << 16);
            }
        }
    }
    __syncthreads();

    // ---- Phase 2: DFT GEMM, wave g owns bins 64g..64g+63, 3-term split product ----
    const int g = w;
    f32x4 accR[2][4], accI[2][4];
    #pragma unroll
    for (int mf = 0; mf < 2; ++mf)
        #pragma unroll
        for (int j = 0; j < 4; ++j) { accR[mf][j] = (f32x4)0.f; accI[mf][j] = (f32x4)0.f; }

    const u16* bh = wsb;
    const u16* bl = wsb + MAIN_U16;

#define LDA(KS, AH, AL)                                                        \
    {                                                                          \
        _Pragma("unroll")                                                      \
        for (int mf = 0; mf < 2; ++mf) {                                       \
            u32 row_ = (u32)(mf * 16 + (lane & 15));                           \
            u32 koff_ = (u32)((KS) * 64 + ((lane >> 4) << 4)) ^ SWA(row_);     \
            u32 byte_ = row_ * AROW + koff_;                                   \
            AH[mf] = *(const bf16x8*)((const char*)sAh + byte_);               \
            AL[mf] = *(const bf16x8*)((const char*)sAl + byte_);               \
        }                                                                      \
    }
#define LDB(KS, J, D)                                                          \
    {                                                                          \
        const int nfR_ = 4 * g + (J), nfI_ = 16 + 4 * g + (J);                 \
        const size_t oR_ = ((size_t)(nfR_ * KS_MAIN + (KS)) * 64 + lane) * 8;  \
        const size_t oI_ = ((size_t)(nfI_ * KS_MAIN + (KS)) * 64 + lane) * 8;  \
        D[0] = *(const bf16x8*)(bh + oR_);                                     \
        D[1] = *(const bf16x8*)(bl + oR_);                                     \
        D[2] = *(const bf16x8*)(bh + oI_);                                     \
        D[3] = *(const bf16x8*)(bl + oI_);                                     \
    }

    bf16x8 aHc[2], aLc[2], aHn[2], aLn[2], Bc[4], Bn[4];
    LDA(0, aHc, aLc);
    LDB(0, 0, Bc);

    for (int ks = 0; ks < KS_MAIN; ++ks) {
        if (ks + 1 < KS_MAIN) LDA(ks + 1, aHn, aLn);   // ds_read a full ks early
        #pragma unroll
        for (int j = 0; j < 4; ++j) {
            if (j < 3) { LDB(ks, j + 1, Bn); }
            else if (ks + 1 < KS_MAIN) { LDB(ks + 1, 0, Bn); }
            #pragma unroll
            for (int mf = 0; mf < 2; ++mf) {
                accR[mf][j] = __builtin_amdgcn_mfma_f32_16x16x32_bf16(aHc[mf], Bc[0], accR[mf][j], 0, 0, 0);
                accR[mf][j] = __builtin_amdgcn_mfma_f32_16x16x32_bf16(aLc[mf], Bc[0], accR[mf][j], 0, 0, 0);
                accR[mf][j] = __builtin_amdgcn_mfma_f32_16x16x32_bf16(aHc[mf], Bc[1], accR[mf][j], 0, 0, 0);
                accI[mf][j] = __builtin_amdgcn_mfma_f32_16x16x32_bf16(aHc[mf], Bc[2], accI[mf][j], 0, 0, 0);
                accI[mf][j] = __builtin_amdgcn_mfma_f32_16x16x32_bf16(aLc[mf], Bc[2], accI[mf][j], 0, 0, 0);
                accI[mf][j] = __builtin_amdgcn_mfma_f32_16x16x32_bf16(aHc[mf], Bc[3], accI[mf][j], 0, 0, 0);
            }
            #pragma unroll
            for (int e = 0; e < 4; ++e) Bc[e] = Bn[e];
        }
        #pragma unroll
        for (int mf = 0; mf < 2; ++mf) { aHc[mf] = aHn[mf]; aLc[mf] = aLn[mf]; }
    }
    __syncthreads();   // all A reads done before overlay

    // ---- Phase 3: power -> LDS bf16 [32][256] overlaying sAh (512-B stride) ----
    #pragma unroll
    for (int mf = 0; mf < 2; ++mf)
        #pragma unroll
        for (int j = 0; j < 4; ++j)
            #pragma unroll
            for (int r = 0; r < 4; ++r) {
                float pR = accR[mf][j][r], pI = accI[mf][j][r];
                float pw = pR * pR + pI * pI;
                u32 row = (u32)(mf * 16 + ((lane >> 4) << 2) + r);
                u32 bin = (u32)(64 * g + j * 16 + (lane & 15));
                u32 byte = row * 512u + bin * 2u;
                byte ^= (row & 7) << 4;
                *(u16*)((char*)sAh + byte) = f2bf(pw);
            }
    __syncthreads();

    // ---- Phase 4: mel GEMM (M=32, N=96 padded, K=256) + log epilogue ----
    const int mfm = w >> 1;            // rows mfm*16..+15
    const int nf0 = (w & 1) ? 3 : 0;   // frag trio {0,1,2} or {3,4,5(pad)}
    f32x4 accM[3];
    #pragma unroll
    for (int j = 0; j < 3; ++j) accM[j] = (f32x4)0.f;

    const u16* melb = wsb + (size_t)(2 * MAIN_U16);
    for (int ks = 0; ks < 8; ++ks) {
        u32 row = (u32)(mfm * 16 + (lane & 15));
        u32 byte = row * 512u + (u32)(ks * 32 + ((lane >> 4) << 3)) * 2u;
        byte ^= (row & 7) << 4;
        bf16x8 aP = *(const bf16x8*)((const char*)sAh + byte);
        #pragma unroll
        for (int j = 0; j < 3; ++j) {
            bf16x8 bM = *(const bf16x8*)(melb + ((size_t)((nf0 + j) * 8 + ks) * 64 + lane) * 8);
            accM[j] = __builtin_amdgcn_mfma_f32_16x16x32_bf16(aP, bM, accM[j], 0, 0, 0);
        }
    }
    #pragma unroll
    for (int j = 0; j < 3; ++j) {
        const int m = (nf0 + j) * 16 + (lane & 15);
        #pragma unroll
        for (int r = 0; r < 4; ++r) {
            const int rowl = mfm * 16 + ((lane >> 4) << 2) + r;
            const int fr = f0 + rowl;
            if (fr < NFRAMES && m < NM) {
                float v = fmaxf(accM[j][r] + EPSF, EPSF);
                out[((size_t)b * NFRAMES + fr) * NM + m] = logf(v);
            }
        }
    }
}

// ---------------- fallback (round-1 fp32 kernel, used if ws too small) ----------------
#define TFB 16
#define NB 256
__global__ __launch_bounds__(256, 3) void fbank_fallback(
    const float* __restrict__ wave, const float* __restrict__ win,
    const float* __restrict__ dftr, const float* __restrict__ dfti,
    const float* __restrict__ melw, float* __restrict__ out) {
    __shared__ float s_fr[TFB][PW];
    __shared__ float s_pw[TFB][NB + 1];
    const int tid = threadIdx.x, wv = tid >> 6, lane = tid & 63;
    const int fbase = blockIdx.x * TFB;
    #pragma unroll
    for (int j = 0; j < TFB / 4; ++j) {
        const int lf = wv * (TFB / 4) + j;
        const int gid = fbase + lf;
        const int bb = gid / NFRAMES;
        const int fr = gid - bb * NFRAMES;
        const float* x = wave + (size_t)bb * TLEN + (size_t)fr * FS;
        float s = 0.f;
        for (int i = lane; i < FL; i += 64) s += x[i];
        #pragma unroll
        for (int off = 32; off >= 1; off >>= 1) s += __shfl_xor(s, off);
        const float mean = s * (1.0f / FL);
        for (int i = lane; i < FL; i += 64) {
            const float xi = x[i];
            const float xm = (i == 0) ? xi : x[i - 1];
            s_fr[lf][i] = (xi - PRE * xm - (1.0f - PRE) * mean) * win[i];
        }
        for (int i = FL + lane; i < PW; i += 64) s_fr[lf][i] = 0.f;
    }
    __syncthreads();
    {
        const int bin = tid;
        const float4* dr4 = (const float4*)(dftr + (size_t)bin * PW);
        const float4* di4 = (const float4*)(dfti + (size_t)bin * PW);
        float accr[TFB], acci[TFB];
        #pragma unroll
        for (int f = 0; f < TFB; ++f) { accr[f] = 0.f; acci[f] = 0.f; }
        for (int k4 = 0; k4 < PW / 4; ++k4) {
            const float4 r = dr4[k4], im = di4[k4];
            #pragma unroll
            for (int f = 0; f < TFB; ++f) {
                const float4 fr = *(const float4*)&s_fr[f][k4 * 4];
                accr[f] += fr.x * r.x + fr.y * r.y + fr.z * r.z + fr.w * r.w;
                acci[f] += fr.x * im.x + fr.y * im.y + fr.z * im.z + fr.w * im.w;
            }
        }
        #pragma unroll
        for (int f = 0; f < TFB; ++f) s_pw[f][bin] = accr[f] * accr[f] + acci[f] * acci[f];
    }
    __syncthreads();
    for (int o = tid; o < TFB * NM; o += 256) {
        const int f = o / NM, m = o - f * NM;
        const float* wm = melw + (size_t)m * 257;
        float acc = 0.f;
        for (int k = 0; k < NB; ++k) acc += s_pw[f][k] * wm[k];
        out[(size_t)(fbase + f) * NM + m] = logf(fmaxf(acc + EPSF, EPSF));
    }
}

extern "C" void kernel_launch(void* const* d_in, const int* in_sizes, int n_in,
                              void* d_out, int out_size, void* d_ws, size_t ws_size,
                              hipStream_t stream) {
    const float* wave = (const float*)d_in[0];
    const float* win  = (const float*)d_in[1];
    const float* dftr = (const float*)d_in[2];
    const float* dfti = (const float*)d_in[3];
    const float* melw = (const float*)d_in[4];
    float* out = (float*)d_out;

    if (ws_size >= WS_NEED) {
        u16* wsb = (u16*)d_ws;
        const int prep_threads = MAIN_GROUPS + MEL_GROUPS;
        prep_kernel<<<(prep_threads + 255) / 256, 256, 0, stream>>>(dftr, dfti, melw, wsb);
        dim3 grid(NTILES, BATCH);
        fbank_mfma<<<grid, 256, 0, stream>>>(wave, win, wsb, out);
    } else {
        const int nblocks = (BATCH * NFRAMES) / TFB;
        fbank_fallback<<<nblocks, 256, 0, stream>>>(wave, win, dftr, dfti, melw, out);
    }
}

// Round 6
// 199.703 us; speedup vs baseline: 10.6969x; 1.0394x over previous
//
#include <hip/hip_runtime.h>
#include <math.h>

// Fbank via split-bf16 MFMA. R6 = R5 minus the stray #pragma placeholder:
// K-chunked LDS (2 x 224 cols -> 28 KB), register diet (no A-prefetch, B
// ping-pong without copies) -> target 4 blocks/CU; vectorized float4 phase-1.

#define BATCH 32
#define TLEN 480000
#define NFRAMES 2998
#define FL 400
#define FS 160
#define PW 512
#define NM 80
#define MT 32                // frames per block
#define NTILES 94            // ceil(2998/32)
#define KS_MAIN 13           // k-steps of 32: covers k<416 (A zero for k>=400)
#define CH0 7                // chunk 0: ks 0..6   (cols 0..223)
#define CH1 6                // chunk 1: ks 7..12  (cols 224..415)
#define CCOL 224             // cols per chunk buffer
#define CROWB 448            // bytes per A row in chunk buffer
#define PRE 0.97f
#define EPSF 1e-6f

typedef short bf16x8 __attribute__((ext_vector_type(8)));
typedef float f32x4 __attribute__((ext_vector_type(4)));
typedef unsigned int u32;
typedef unsigned short u16;
typedef u32 u32x4 __attribute__((ext_vector_type(4)));

#define MAIN_GROUPS (32 * KS_MAIN * 64)   // fragment-groups (re+im x 13 ks)
#define MAIN_U16 (MAIN_GROUPS * 8)        // u16 per plane (hi, lo)
#define MEL_GROUPS (6 * 8 * 64)
#define MEL_U16 (MEL_GROUPS * 8)
#define WS_NEED ((size_t)(2 * MAIN_U16 + MEL_U16) * 2)   // ~901 KB

__device__ __forceinline__ u16 f2bf(float f) {
    u32 u = __builtin_bit_cast(u32, f);
    return (u16)((u + 0x7FFFu + ((u >> 16) & 1u)) >> 16);
}
__device__ __forceinline__ float bf2f(u16 h) {
    u32 u = ((u32)h) << 16;
    return __builtin_bit_cast(float, u);
}

// ---------------- prep: pack B (DFT re/im, hi+lo planes) + mel weights ----------------
__global__ void prep_kernel(const float* __restrict__ dftr, const float* __restrict__ dfti,
                            const float* __restrict__ melw, u16* __restrict__ wsb) {
    int idx = blockIdx.x * 256 + threadIdx.x;
    if (idx < MAIN_GROUPS) {
        int nf = idx / (KS_MAIN * 64);
        int rem = idx - nf * (KS_MAIN * 64);
        int ks = rem >> 6;
        int l  = rem & 63;
        int n  = nf * 16 + (l & 15);          // 0..511: re 0..255, im 256..511
        int k  = ks * 32 + ((l >> 4) << 3);   // < 416 <= 512
        const float* src = (n < 256) ? (dftr + (size_t)n * PW + k)
                                     : (dfti + (size_t)(n - 256) * PW + k);
        u16* dh = wsb + (size_t)idx * 8;
        u16* dl = wsb + (size_t)MAIN_U16 + (size_t)idx * 8;
        #pragma unroll
        for (int e = 0; e < 8; ++e) {
            float x = src[e];
            u16 h = f2bf(x);
            dh[e] = h;
            dl[e] = f2bf(x - bf2f(h));
        }
    } else {
        int j = idx - MAIN_GROUPS;
        if (j < MEL_GROUPS) {
            int nf = j / (8 * 64);
            int ks = (j >> 6) & 7;
            int l  = j & 63;
            int n  = nf * 16 + (l & 15);
            int k  = ks * 32 + ((l >> 4) << 3);
            u16* dst = wsb + (size_t)(2 * MAIN_U16) + (size_t)j * 8;
            if (n < NM) {
                const float* src = melw + (size_t)n * 257 + k;   // col 256 never read
                #pragma unroll
                for (int e = 0; e < 8; ++e) dst[e] = f2bf(src[e]);
            } else {
                #pragma unroll
                for (int e = 0; e < 8; ++e) dst[e] = 0;
            }
        }
    }
}

// A-chunk swizzle for 448-B stride: rows -> 4-bank-group rotation (2-way residual = free)
#define SWA(row) ((((u32)(row) >> 1) & 3u) << 4)

#define MFMA12(BU, J)                                                                       \
    _Pragma("unroll")                                                                       \
    for (int mf = 0; mf < 2; ++mf) {                                                        \
        accR[mf][J] = __builtin_amdgcn_mfma_f32_16x16x32_bf16(aH[mf], BU[0], accR[mf][J], 0, 0, 0); \
        accR[mf][J] = __builtin_amdgcn_mfma_f32_16x16x32_bf16(aL[mf], BU[0], accR[mf][J], 0, 0, 0); \
        accR[mf][J] = __builtin_amdgcn_mfma_f32_16x16x32_bf16(aH[mf], BU[1], accR[mf][J], 0, 0, 0); \
        accI[mf][J] = __builtin_amdgcn_mfma_f32_16x16x32_bf16(aH[mf], BU[2], accI[mf][J], 0, 0, 0); \
        accI[mf][J] = __builtin_amdgcn_mfma_f32_16x16x32_bf16(aL[mf], BU[2], accI[mf][J], 0, 0, 0); \
        accI[mf][J] = __builtin_amdgcn_mfma_f32_16x16x32_bf16(aH[mf], BU[3], accI[mf][J], 0, 0, 0); \
    }

template<int KS0, int NKS>
__device__ __forceinline__ void dft_chunk(
    const u16* sAh, const u16* sAl,
    const u16* __restrict__ bh, const u16* __restrict__ bl,
    int g, int lane, f32x4 (&accR)[2][4], f32x4 (&accI)[2][4]) {

    bf16x8 aH[2], aL[2], BA[4], BB[4];

#define LDA_C(KS)                                                              \
    { _Pragma("unroll")                                                        \
      for (int mf = 0; mf < 2; ++mf) {                                         \
        u32 row_ = (u32)(mf * 16 + (lane & 15));                               \
        u32 koff_ = ((u32)((KS) * 64 + ((lane >> 4) << 4))) ^ SWA(row_);       \
        u32 byte_ = row_ * CROWB + koff_;                                      \
        aH[mf] = *(const bf16x8*)((const char*)sAh + byte_);                   \
        aL[mf] = *(const bf16x8*)((const char*)sAl + byte_);                   \
      } }
#define LDB_C(KSG, J, D)                                                       \
    {                                                                          \
        const int nfR_ = 4 * g + (J), nfI_ = 16 + 4 * g + (J);                 \
        const size_t oR_ = ((size_t)(nfR_ * KS_MAIN + (KSG)) * 64 + lane) * 8; \
        const size_t oI_ = ((size_t)(nfI_ * KS_MAIN + (KSG)) * 64 + lane) * 8; \
        D[0] = *(const bf16x8*)(bh + oR_);                                     \
        D[1] = *(const bf16x8*)(bl + oR_);                                     \
        D[2] = *(const bf16x8*)(bh + oI_);                                     \
        D[3] = *(const bf16x8*)(bl + oI_);                                     \
    }

    LDB_C(KS0, 0, BA);
    for (int ks = 0; ks < NKS; ++ks) {
        LDA_C(ks);
        LDB_C(KS0 + ks, 1, BB);
        MFMA12(BA, 0);
        LDB_C(KS0 + ks, 2, BA);
        MFMA12(BB, 1);
        LDB_C(KS0 + ks, 3, BB);
        MFMA12(BA, 2);
        if (ks + 1 < NKS) LDB_C(KS0 + ks + 1, 0, BA);
        MFMA12(BB, 3);
    }
#undef LDA_C
#undef LDB_C
}

// ---------------- main fused kernel ----------------
__global__ __launch_bounds__(256, 4) void fbank_mfma(
    const float* __restrict__ wave, const float* __restrict__ win,
    const u16* __restrict__ wsb, float* __restrict__ out) {
    __shared__ u16 sbuf[MT * CCOL * 2];          // 28,672 B (hi plane then lo plane)
    u16* sAh = sbuf;
    u16* sAl = sbuf + MT * CCOL;

    const int tid = threadIdx.x, w = tid >> 6, lane = tid & 63;
    const int b = blockIdx.y;
    const int f0 = blockIdx.x * MT;
    const float* wb = wave + (size_t)b * TLEN;
    const float4* win4 = (const float4*)win;

    const int h  = lane >> 5;      // frame half (2 frames per step)
    const int gg = lane & 31;      // group within half

    // ---- Phase 1a: means (4 steps x 2 frames per wave) ----
    float mean[4];
    #pragma unroll
    for (int s = 0; s < 4; ++s) {
        const int fr = f0 + w * 8 + 2 * s + h;
        float acc = 0.f;
        if (fr < NFRAMES) {
            const float4* x4 = (const float4*)(wb + (size_t)fr * FS);
            float4 a = x4[gg], c = x4[gg + 32], d = x4[gg + 64];
            acc = a.x + a.y + a.z + a.w + c.x + c.y + c.z + c.w + d.x + d.y + d.z + d.w;
            if (gg < 4) { float4 e = x4[gg + 96]; acc += e.x + e.y + e.z + e.w; }
        }
        #pragma unroll
        for (int o = 16; o; o >>= 1) acc += __shfl_xor(acc, o);
        mean[s] = acc * (1.0f / FL);
    }

    // ---- Phase 1b: window+preemph chunk 0 (samples 0..223), write swizzled ----
    #pragma unroll
    for (int s = 0; s < 4; ++s) {
        const int rr = w * 8 + 2 * s + h;
        const int fr = f0 + rr;
        const bool valid = fr < NFRAMES;
        const float* x = wb + (size_t)fr * FS;
        const float4* x4 = (const float4*)x;
        if (gg < 28) {
            float4 v0 = {0,0,0,0}, v1 = {0,0,0,0};
            if (valid) { v0 = x4[2 * gg]; v1 = x4[2 * gg + 1]; }
            float4 w0 = win4[2 * gg], w1 = win4[2 * gg + 1];
            float xpn = __shfl(v1.w, lane - 1);
            float xprev = (gg == 0) ? v0.x : xpn;
            const float mc = (1.0f - PRE) * mean[s];
            float ys[8];
            ys[0] = (v0.x - PRE * xprev - mc) * w0.x;
            ys[1] = (v0.y - PRE * v0.x - mc) * w0.y;
            ys[2] = (v0.z - PRE * v0.y - mc) * w0.z;
            ys[3] = (v0.w - PRE * v0.z - mc) * w0.w;
            ys[4] = (v1.x - PRE * v0.w - mc) * w1.x;
            ys[5] = (v1.y - PRE * v1.x - mc) * w1.y;
            ys[6] = (v1.z - PRE * v1.y - mc) * w1.z;
            ys[7] = (v1.w - PRE * v1.z - mc) * w1.w;
            u32x4 hv, lv;
            #pragma unroll
            for (int e = 0; e < 4; ++e) {
                u16 h0 = f2bf(ys[2 * e]), h1 = f2bf(ys[2 * e + 1]);
                hv[e] = (u32)h0 | ((u32)h1 << 16);
                u16 l0 = f2bf(ys[2 * e] - bf2f(h0)), l1 = f2bf(ys[2 * e + 1] - bf2f(h1));
                lv[e] = (u32)l0 | ((u32)l1 << 16);
            }
            u32 byte = (u32)rr * CROWB + (((u32)gg * 16u) ^ SWA(rr));
            *(u32x4*)((char*)sAh + byte) = hv;
            *(u32x4*)((char*)sAl + byte) = lv;
        }
    }
    __syncthreads();

    // ---- Phase 2a: DFT GEMM chunk 0 (ks 0..6) ----
    const int g = w;
    f32x4 accR[2][4], accI[2][4];
    #pragma unroll
    for (int mf = 0; mf < 2; ++mf)
        #pragma unroll
        for (int j = 0; j < 4; ++j) { accR[mf][j] = (f32x4)0.f; accI[mf][j] = (f32x4)0.f; }

    dft_chunk<0, CH0>(sAh, sAl, wsb, wsb + MAIN_U16, g, lane, accR, accI);
    __syncthreads();

    // ---- Phase 1c: window+preemph chunk 1 (samples 224..415; >=400 zero) ----
    #pragma unroll
    for (int s = 0; s < 4; ++s) {
        const int rr = w * 8 + 2 * s + h;
        const int fr = f0 + rr;
        const bool valid = fr < NFRAMES;
        const float* x = wb + (size_t)fr * FS;
        const float4* x4 = (const float4*)x;
        if (gg < 24) {
            float4 v0 = {0,0,0,0}, v1 = {0,0,0,0}, w0 = {0,0,0,0}, w1 = {0,0,0,0};
            const bool live = gg < 22;                       // samples < 400
            if (live) {
                if (valid) { v0 = x4[56 + 2 * gg]; v1 = x4[57 + 2 * gg]; }
                w0 = win4[56 + 2 * gg]; w1 = win4[57 + 2 * gg];
            }
            float xpn = __shfl(v1.w, lane - 1);
            float xprev = xpn;
            if (gg == 0) xprev = valid ? x[223] : 0.f;
            const float mc = (1.0f - PRE) * mean[s];
            float ys[8];
            if (live) {
                ys[0] = (v0.x - PRE * xprev - mc) * w0.x;
                ys[1] = (v0.y - PRE * v0.x - mc) * w0.y;
                ys[2] = (v0.z - PRE * v0.y - mc) * w0.z;
                ys[3] = (v0.w - PRE * v0.z - mc) * w0.w;
                ys[4] = (v1.x - PRE * v0.w - mc) * w1.x;
                ys[5] = (v1.y - PRE * v1.x - mc) * w1.y;
                ys[6] = (v1.z - PRE * v1.y - mc) * w1.z;
                ys[7] = (v1.w - PRE * v1.z - mc) * w1.w;
            } else {
                #pragma unroll
                for (int e = 0; e < 8; ++e) ys[e] = 0.f;
            }
            u32x4 hv, lv;
            #pragma unroll
            for (int e = 0; e < 4; ++e) {
                u16 h0 = f2bf(ys[2 * e]), h1 = f2bf(ys[2 * e + 1]);
                hv[e] = (u32)h0 | ((u32)h1 << 16);
                u16 l0 = f2bf(ys[2 * e] - bf2f(h0)), l1 = f2bf(ys[2 * e + 1] - bf2f(h1));
                lv[e] = (u32)l0 | ((u32)l1 << 16);
            }
            u32 byte = (u32)rr * CROWB + (((u32)gg * 16u) ^ SWA(rr));
            *(u32x4*)((char*)sAh + byte) = hv;
            *(u32x4*)((char*)sAl + byte) = lv;
        }
    }
    __syncthreads();

    // ---- Phase 2b: DFT GEMM chunk 1 (ks 7..12) ----
    dft_chunk<CH0, CH1>(sAh, sAl, wsb, wsb + MAIN_U16, g, lane, accR, accI);
    __syncthreads();

    // ---- Phase 3: power -> LDS bf16 [32][256] overlaying sbuf (512-B stride) ----
    #pragma unroll
    for (int mf = 0; mf < 2; ++mf)
        #pragma unroll
        for (int j = 0; j < 4; ++j)
            #pragma unroll
            for (int r = 0; r < 4; ++r) {
                float pR = accR[mf][j][r], pI = accI[mf][j][r];
                float pw = pR * pR + pI * pI;
                u32 row = (u32)(mf * 16 + ((lane >> 4) << 2) + r);
                u32 bin = (u32)(64 * g + j * 16 + (lane & 15));
                u32 byte = (row * 512u + bin * 2u) ^ ((row & 7) << 4);
                *(u16*)((char*)sbuf + byte) = f2bf(pw);
            }
    __syncthreads();

    // ---- Phase 4: mel GEMM (M=32, N=96 padded, K=256) + log epilogue ----
    const int mfm = w >> 1;
    const int nf0 = (w & 1) ? 3 : 0;
    f32x4 accM[3];
    #pragma unroll
    for (int j = 0; j < 3; ++j) accM[j] = (f32x4)0.f;

    const u16* melb = wsb + (size_t)(2 * MAIN_U16);
    for (int ks = 0; ks < 8; ++ks) {
        u32 row = (u32)(mfm * 16 + (lane & 15));
        u32 byte = (row * 512u + (u32)(ks * 32 + ((lane >> 4) << 3)) * 2u) ^ ((row & 7) << 4);
        bf16x8 aP = *(const bf16x8*)((const char*)sbuf + byte);
        #pragma unroll
        for (int j = 0; j < 3; ++j) {
            bf16x8 bM = *(const bf16x8*)(melb + ((size_t)((nf0 + j) * 8 + ks) * 64 + lane) * 8);
            accM[j] = __builtin_amdgcn_mfma_f32_16x16x32_bf16(aP, bM, accM[j], 0, 0, 0);
        }
    }
    #pragma unroll
    for (int j = 0; j < 3; ++j) {
        const int m = (nf0 + j) * 16 + (lane & 15);
        #pragma unroll
        for (int r = 0; r < 4; ++r) {
            const int rowl = mfm * 16 + ((lane >> 4) << 2) + r;
            const int fr = f0 + rowl;
            if (fr < NFRAMES && m < NM) {
                float v = fmaxf(accM[j][r] + EPSF, EPSF);
                out[((size_t)b * NFRAMES + fr) * NM + m] = logf(v);
            }
        }
    }
}

// ---------------- fallback (round-1 fp32 kernel, used if ws too small) ----------------
#define TFB 16
#define NB 256
__global__ __launch_bounds__(256, 3) void fbank_fallback(
    const float* __restrict__ wave, const float* __restrict__ win,
    const float* __restrict__ dftr, const float* __restrict__ dfti,
    const float* __restrict__ melw, float* __restrict__ out) {
    __shared__ float s_fr[TFB][PW];
    __shared__ float s_pw[TFB][NB + 1];
    const int tid = threadIdx.x, wv = tid >> 6, lane = tid & 63;
    const int fbase = blockIdx.x * TFB;
    #pragma unroll
    for (int j = 0; j < TFB / 4; ++j) {
        const int lf = wv * (TFB / 4) + j;
        const int gid = fbase + lf;
        const int bb = gid / NFRAMES;
        const int fr = gid - bb * NFRAMES;
        const float* x = wave + (size_t)bb * TLEN + (size_t)fr * FS;
        float s = 0.f;
        for (int i = lane; i < FL; i += 64) s += x[i];
        #pragma unroll
        for (int off = 32; off >= 1; off >>= 1) s += __shfl_xor(s, off);
        const float mean = s * (1.0f / FL);
        for (int i = lane; i < FL; i += 64) {
            const float xi = x[i];
            const float xm = (i == 0) ? xi : x[i - 1];
            s_fr[lf][i] = (xi - PRE * xm - (1.0f - PRE) * mean) * win[i];
        }
        for (int i = FL + lane; i < PW; i += 64) s_fr[lf][i] = 0.f;
    }
    __syncthreads();
    {
        const int bin = tid;
        const float4* dr4 = (const float4*)(dftr + (size_t)bin * PW);
        const float4* di4 = (const float4*)(dfti + (size_t)bin * PW);
        float accr[TFB], acci[TFB];
        #pragma unroll
        for (int f = 0; f < TFB; ++f) { accr[f] = 0.f; acci[f] = 0.f; }
        for (int k4 = 0; k4 < PW / 4; ++k4) {
            const float4 r = dr4[k4], im = di4[k4];
            #pragma unroll
            for (int f = 0; f < TFB; ++f) {
                const float4 fr = *(const float4*)&s_fr[f][k4 * 4];
                accr[f] += fr.x * r.x + fr.y * r.y + fr.z * r.z + fr.w * r.w;
                acci[f] += fr.x * im.x + fr.y * im.y + fr.z * im.z + fr.w * im.w;
            }
        }
        #pragma unroll
        for (int f = 0; f < TFB; ++f) s_pw[f][bin] = accr[f] * accr[f] + acci[f] * acci[f];
    }
    __syncthreads();
    for (int o = tid; o < TFB * NM; o += 256) {
        const int f = o / NM, m = o - f * NM;
        const float* wm = melw + (size_t)m * 257;
        float acc = 0.f;
        for (int k = 0; k < NB; ++k) acc += s_pw[f][k] * wm[k];
        out[(size_t)(fbase + f) * NM + m] = logf(fmaxf(acc + EPSF, EPSF));
    }
}

extern "C" void kernel_launch(void* const* d_in, const int* in_sizes, int n_in,
                              void* d_out, int out_size, void* d_ws, size_t ws_size,
                              hipStream_t stream) {
    const float* wave = (const float*)d_in[0];
    const float* win  = (const float*)d_in[1];
    const float* dftr = (const float*)d_in[2];
    const float* dfti = (const float*)d_in[3];
    const float* melw = (const float*)d_in[4];
    float* out = (float*)d_out;

    if (ws_size >= WS_NEED) {
        u16* wsb = (u16*)d_ws;
        const int prep_threads = MAIN_GROUPS + MEL_GROUPS;
        prep_kernel<<<(prep_threads + 255) / 256, 256, 0, stream>>>(dftr, dfti, melw, wsb);
        dim3 grid(NTILES, BATCH);
        fbank_mfma<<<grid, 256, 0, stream>>>(wave, win, wsb, out);
    } else {
        const int nblocks = (BATCH * NFRAMES) / TFB;
        fbank_fallback<<<nblocks, 256, 0, stream>>>(wave, win, dftr, dfti, melw, out);
    }
}

// Round 7
// 158.412 us; speedup vs baseline: 13.4851x; 1.2607x over previous
//
#include <hip/hip_runtime.h>
#include <math.h>

// Fbank via split-bf16 MFMA. R7 = R6 with __launch_bounds__(256,3):
// R6's (256,4) forced ~192 MB of scratch spill (WRITE_SIZE 30->222 MB).
// 3 waves/SIMD budget (~170 regs) holds 64 AGPR accs + working set spill-free.

#define BATCH 32
#define TLEN 480000
#define NFRAMES 2998
#define FL 400
#define FS 160
#define PW 512
#define NM 80
#define MT 32                // frames per block
#define NTILES 94            // ceil(2998/32)
#define KS_MAIN 13           // k-steps of 32: covers k<416 (A zero for k>=400)
#define CH0 7                // chunk 0: ks 0..6   (cols 0..223)
#define CH1 6                // chunk 1: ks 7..12  (cols 224..415)
#define CCOL 224             // cols per chunk buffer
#define CROWB 448            // bytes per A row in chunk buffer
#define PRE 0.97f
#define EPSF 1e-6f

typedef short bf16x8 __attribute__((ext_vector_type(8)));
typedef float f32x4 __attribute__((ext_vector_type(4)));
typedef unsigned int u32;
typedef unsigned short u16;
typedef u32 u32x4 __attribute__((ext_vector_type(4)));

#define MAIN_GROUPS (32 * KS_MAIN * 64)   // fragment-groups (re+im x 13 ks)
#define MAIN_U16 (MAIN_GROUPS * 8)        // u16 per plane (hi, lo)
#define MEL_GROUPS (6 * 8 * 64)
#define MEL_U16 (MEL_GROUPS * 8)
#define WS_NEED ((size_t)(2 * MAIN_U16 + MEL_U16) * 2)   // ~901 KB

__device__ __forceinline__ u16 f2bf(float f) {
    u32 u = __builtin_bit_cast(u32, f);
    return (u16)((u + 0x7FFFu + ((u >> 16) & 1u)) >> 16);
}
__device__ __forceinline__ float bf2f(u16 h) {
    u32 u = ((u32)h) << 16;
    return __builtin_bit_cast(float, u);
}

// ---------------- prep: pack B (DFT re/im, hi+lo planes) + mel weights ----------------
__global__ void prep_kernel(const float* __restrict__ dftr, const float* __restrict__ dfti,
                            const float* __restrict__ melw, u16* __restrict__ wsb) {
    int idx = blockIdx.x * 256 + threadIdx.x;
    if (idx < MAIN_GROUPS) {
        int nf = idx / (KS_MAIN * 64);
        int rem = idx - nf * (KS_MAIN * 64);
        int ks = rem >> 6;
        int l  = rem & 63;
        int n  = nf * 16 + (l & 15);          // 0..511: re 0..255, im 256..511
        int k  = ks * 32 + ((l >> 4) << 3);   // < 416 <= 512
        const float* src = (n < 256) ? (dftr + (size_t)n * PW + k)
                                     : (dfti + (size_t)(n - 256) * PW + k);
        u16* dh = wsb + (size_t)idx * 8;
        u16* dl = wsb + (size_t)MAIN_U16 + (size_t)idx * 8;
        #pragma unroll
        for (int e = 0; e < 8; ++e) {
            float x = src[e];
            u16 h = f2bf(x);
            dh[e] = h;
            dl[e] = f2bf(x - bf2f(h));
        }
    } else {
        int j = idx - MAIN_GROUPS;
        if (j < MEL_GROUPS) {
            int nf = j / (8 * 64);
            int ks = (j >> 6) & 7;
            int l  = j & 63;
            int n  = nf * 16 + (l & 15);
            int k  = ks * 32 + ((l >> 4) << 3);
            u16* dst = wsb + (size_t)(2 * MAIN_U16) + (size_t)j * 8;
            if (n < NM) {
                const float* src = melw + (size_t)n * 257 + k;   // col 256 never read
                #pragma unroll
                for (int e = 0; e < 8; ++e) dst[e] = f2bf(src[e]);
            } else {
                #pragma unroll
                for (int e = 0; e < 8; ++e) dst[e] = 0;
            }
        }
    }
}

// A-chunk swizzle for 448-B stride: rows -> 4-bank-group rotation (2-way residual = free)
#define SWA(row) ((((u32)(row) >> 1) & 3u) << 4)

#define MFMA12(BU, J)                                                                       \
    _Pragma("unroll")                                                                       \
    for (int mf = 0; mf < 2; ++mf) {                                                        \
        accR[mf][J] = __builtin_amdgcn_mfma_f32_16x16x32_bf16(aH[mf], BU[0], accR[mf][J], 0, 0, 0); \
        accR[mf][J] = __builtin_amdgcn_mfma_f32_16x16x32_bf16(aL[mf], BU[0], accR[mf][J], 0, 0, 0); \
        accR[mf][J] = __builtin_amdgcn_mfma_f32_16x16x32_bf16(aH[mf], BU[1], accR[mf][J], 0, 0, 0); \
        accI[mf][J] = __builtin_amdgcn_mfma_f32_16x16x32_bf16(aH[mf], BU[2], accI[mf][J], 0, 0, 0); \
        accI[mf][J] = __builtin_amdgcn_mfma_f32_16x16x32_bf16(aL[mf], BU[2], accI[mf][J], 0, 0, 0); \
        accI[mf][J] = __builtin_amdgcn_mfma_f32_16x16x32_bf16(aH[mf], BU[3], accI[mf][J], 0, 0, 0); \
    }

template<int KS0, int NKS>
__device__ __forceinline__ void dft_chunk(
    const u16* sAh, const u16* sAl,
    const u16* __restrict__ bh, const u16* __restrict__ bl,
    int g, int lane, f32x4 (&accR)[2][4], f32x4 (&accI)[2][4]) {

    bf16x8 aH[2], aL[2], BA[4], BB[4];

#define LDA_C(KS)                                                              \
    { _Pragma("unroll")                                                        \
      for (int mf = 0; mf < 2; ++mf) {                                         \
        u32 row_ = (u32)(mf * 16 + (lane & 15));                               \
        u32 koff_ = ((u32)((KS) * 64 + ((lane >> 4) << 4))) ^ SWA(row_);       \
        u32 byte_ = row_ * CROWB + koff_;                                      \
        aH[mf] = *(const bf16x8*)((const char*)sAh + byte_);                   \
        aL[mf] = *(const bf16x8*)((const char*)sAl + byte_);                   \
      } }
#define LDB_C(KSG, J, D)                                                       \
    {                                                                          \
        const int nfR_ = 4 * g + (J), nfI_ = 16 + 4 * g + (J);                 \
        const size_t oR_ = ((size_t)(nfR_ * KS_MAIN + (KSG)) * 64 + lane) * 8; \
        const size_t oI_ = ((size_t)(nfI_ * KS_MAIN + (KSG)) * 64 + lane) * 8; \
        D[0] = *(const bf16x8*)(bh + oR_);                                     \
        D[1] = *(const bf16x8*)(bl + oR_);                                     \
        D[2] = *(const bf16x8*)(bh + oI_);                                     \
        D[3] = *(const bf16x8*)(bl + oI_);                                     \
    }

    LDB_C(KS0, 0, BA);
    for (int ks = 0; ks < NKS; ++ks) {
        LDA_C(ks);
        LDB_C(KS0 + ks, 1, BB);
        MFMA12(BA, 0);
        LDB_C(KS0 + ks, 2, BA);
        MFMA12(BB, 1);
        LDB_C(KS0 + ks, 3, BB);
        MFMA12(BA, 2);
        if (ks + 1 < NKS) LDB_C(KS0 + ks + 1, 0, BA);
        MFMA12(BB, 3);
    }
#undef LDA_C
#undef LDB_C
}

// ---------------- main fused kernel ----------------
__global__ __launch_bounds__(256, 3) void fbank_mfma(
    const float* __restrict__ wave, const float* __restrict__ win,
    const u16* __restrict__ wsb, float* __restrict__ out) {
    __shared__ u16 sbuf[MT * CCOL * 2];          // 28,672 B (hi plane then lo plane)
    u16* sAh = sbuf;
    u16* sAl = sbuf + MT * CCOL;

    const int tid = threadIdx.x, w = tid >> 6, lane = tid & 63;
    const int b = blockIdx.y;
    const int f0 = blockIdx.x * MT;
    const float* wb = wave + (size_t)b * TLEN;
    const float4* win4 = (const float4*)win;

    const int h  = lane >> 5;      // frame half (2 frames per step)
    const int gg = lane & 31;      // group within half

    // ---- Phase 1a: means (4 steps x 2 frames per wave) ----
    float mean[4];
    #pragma unroll
    for (int s = 0; s < 4; ++s) {
        const int fr = f0 + w * 8 + 2 * s + h;
        float acc = 0.f;
        if (fr < NFRAMES) {
            const float4* x4 = (const float4*)(wb + (size_t)fr * FS);
            float4 a = x4[gg], c = x4[gg + 32], d = x4[gg + 64];
            acc = a.x + a.y + a.z + a.w + c.x + c.y + c.z + c.w + d.x + d.y + d.z + d.w;
            if (gg < 4) { float4 e = x4[gg + 96]; acc += e.x + e.y + e.z + e.w; }
        }
        #pragma unroll
        for (int o = 16; o; o >>= 1) acc += __shfl_xor(acc, o);
        mean[s] = acc * (1.0f / FL);
    }

    // ---- Phase 1b: window+preemph chunk 0 (samples 0..223), write swizzled ----
    #pragma unroll
    for (int s = 0; s < 4; ++s) {
        const int rr = w * 8 + 2 * s + h;
        const int fr = f0 + rr;
        const bool valid = fr < NFRAMES;
        const float* x = wb + (size_t)fr * FS;
        const float4* x4 = (const float4*)x;
        if (gg < 28) {
            float4 v0 = {0,0,0,0}, v1 = {0,0,0,0};
            if (valid) { v0 = x4[2 * gg]; v1 = x4[2 * gg + 1]; }
            float4 w0 = win4[2 * gg], w1 = win4[2 * gg + 1];
            float xpn = __shfl(v1.w, lane - 1);
            float xprev = (gg == 0) ? v0.x : xpn;
            const float mc = (1.0f - PRE) * mean[s];
            float ys[8];
            ys[0] = (v0.x - PRE * xprev - mc) * w0.x;
            ys[1] = (v0.y - PRE * v0.x - mc) * w0.y;
            ys[2] = (v0.z - PRE * v0.y - mc) * w0.z;
            ys[3] = (v0.w - PRE * v0.z - mc) * w0.w;
            ys[4] = (v1.x - PRE * v0.w - mc) * w1.x;
            ys[5] = (v1.y - PRE * v1.x - mc) * w1.y;
            ys[6] = (v1.z - PRE * v1.y - mc) * w1.z;
            ys[7] = (v1.w - PRE * v1.z - mc) * w1.w;
            u32x4 hv, lv;
            #pragma unroll
            for (int e = 0; e < 4; ++e) {
                u16 h0 = f2bf(ys[2 * e]), h1 = f2bf(ys[2 * e + 1]);
                hv[e] = (u32)h0 | ((u32)h1 << 16);
                u16 l0 = f2bf(ys[2 * e] - bf2f(h0)), l1 = f2bf(ys[2 * e + 1] - bf2f(h1));
                lv[e] = (u32)l0 | ((u32)l1 << 16);
            }
            u32 byte = (u32)rr * CROWB + (((u32)gg * 16u) ^ SWA(rr));
            *(u32x4*)((char*)sAh + byte) = hv;
            *(u32x4*)((char*)sAl + byte) = lv;
        }
    }
    __syncthreads();

    // ---- Phase 2a: DFT GEMM chunk 0 (ks 0..6) ----
    const int g = w;
    f32x4 accR[2][4], accI[2][4];
    #pragma unroll
    for (int mf = 0; mf < 2; ++mf)
        #pragma unroll
        for (int j = 0; j < 4; ++j) { accR[mf][j] = (f32x4)0.f; accI[mf][j] = (f32x4)0.f; }

    dft_chunk<0, CH0>(sAh, sAl, wsb, wsb + MAIN_U16, g, lane, accR, accI);
    __syncthreads();

    // ---- Phase 1c: window+preemph chunk 1 (samples 224..415; >=400 zero) ----
    #pragma unroll
    for (int s = 0; s < 4; ++s) {
        const int rr = w * 8 + 2 * s + h;
        const int fr = f0 + rr;
        const bool valid = fr < NFRAMES;
        const float* x = wb + (size_t)fr * FS;
        const float4* x4 = (const float4*)x;
        if (gg < 24) {
            float4 v0 = {0,0,0,0}, v1 = {0,0,0,0}, w0 = {0,0,0,0}, w1 = {0,0,0,0};
            const bool live = gg < 22;                       // samples < 400
            if (live) {
                if (valid) { v0 = x4[56 + 2 * gg]; v1 = x4[57 + 2 * gg]; }
                w0 = win4[56 + 2 * gg]; w1 = win4[57 + 2 * gg];
            }
            float xpn = __shfl(v1.w, lane - 1);
            float xprev = xpn;
            if (gg == 0) xprev = valid ? x[223] : 0.f;
            const float mc = (1.0f - PRE) * mean[s];
            float ys[8];
            if (live) {
                ys[0] = (v0.x - PRE * xprev - mc) * w0.x;
                ys[1] = (v0.y - PRE * v0.x - mc) * w0.y;
                ys[2] = (v0.z - PRE * v0.y - mc) * w0.z;
                ys[3] = (v0.w - PRE * v0.z - mc) * w0.w;
                ys[4] = (v1.x - PRE * v0.w - mc) * w1.x;
                ys[5] = (v1.y - PRE * v1.x - mc) * w1.y;
                ys[6] = (v1.z - PRE * v1.y - mc) * w1.z;
                ys[7] = (v1.w - PRE * v1.z - mc) * w1.w;
            } else {
                #pragma unroll
                for (int e = 0; e < 8; ++e) ys[e] = 0.f;
            }
            u32x4 hv, lv;
            #pragma unroll
            for (int e = 0; e < 4; ++e) {
                u16 h0 = f2bf(ys[2 * e]), h1 = f2bf(ys[2 * e + 1]);
                hv[e] = (u32)h0 | ((u32)h1 << 16);
                u16 l0 = f2bf(ys[2 * e] - bf2f(h0)), l1 = f2bf(ys[2 * e + 1] - bf2f(h1));
                lv[e] = (u32)l0 | ((u32)l1 << 16);
            }
            u32 byte = (u32)rr * CROWB + (((u32)gg * 16u) ^ SWA(rr));
            *(u32x4*)((char*)sAh + byte) = hv;
            *(u32x4*)((char*)sAl + byte) = lv;
        }
    }
    __syncthreads();

    // ---- Phase 2b: DFT GEMM chunk 1 (ks 7..12) ----
    dft_chunk<CH0, CH1>(sAh, sAl, wsb, wsb + MAIN_U16, g, lane, accR, accI);
    __syncthreads();

    // ---- Phase 3: power -> LDS bf16 [32][256] overlaying sbuf (512-B stride) ----
    #pragma unroll
    for (int mf = 0; mf < 2; ++mf)
        #pragma unroll
        for (int j = 0; j < 4; ++j)
            #pragma unroll
            for (int r = 0; r < 4; ++r) {
                float pR = accR[mf][j][r], pI = accI[mf][j][r];
                float pw = pR * pR + pI * pI;
                u32 row = (u32)(mf * 16 + ((lane >> 4) << 2) + r);
                u32 bin = (u32)(64 * g + j * 16 + (lane & 15));
                u32 byte = (row * 512u + bin * 2u) ^ ((row & 7) << 4);
                *(u16*)((char*)sbuf + byte) = f2bf(pw);
            }
    __syncthreads();

    // ---- Phase 4: mel GEMM (M=32, N=96 padded, K=256) + log epilogue ----
    const int mfm = w >> 1;
    const int nf0 = (w & 1) ? 3 : 0;
    f32x4 accM[3];
    #pragma unroll
    for (int j = 0; j < 3; ++j) accM[j] = (f32x4)0.f;

    const u16* melb = wsb + (size_t)(2 * MAIN_U16);
    for (int ks = 0; ks < 8; ++ks) {
        u32 row = (u32)(mfm * 16 + (lane & 15));
        u32 byte = (row * 512u + (u32)(ks * 32 + ((lane >> 4) << 3)) * 2u) ^ ((row & 7) << 4);
        bf16x8 aP = *(const bf16x8*)((const char*)sbuf + byte);
        #pragma unroll
        for (int j = 0; j < 3; ++j) {
            bf16x8 bM = *(const bf16x8*)(melb + ((size_t)((nf0 + j) * 8 + ks) * 64 + lane) * 8);
            accM[j] = __builtin_amdgcn_mfma_f32_16x16x32_bf16(aP, bM, accM[j], 0, 0, 0);
        }
    }
    #pragma unroll
    for (int j = 0; j < 3; ++j) {
        const int m = (nf0 + j) * 16 + (lane & 15);
        #pragma unroll
        for (int r = 0; r < 4; ++r) {
            const int rowl = mfm * 16 + ((lane >> 4) << 2) + r;
            const int fr = f0 + rowl;
            if (fr < NFRAMES && m < NM) {
                float v = fmaxf(accM[j][r] + EPSF, EPSF);
                out[((size_t)b * NFRAMES + fr) * NM + m] = logf(v);
            }
        }
    }
}

// ---------------- fallback (round-1 fp32 kernel, used if ws too small) ----------------
#define TFB 16
#define NB 256
__global__ __launch_bounds__(256, 3) void fbank_fallback(
    const float* __restrict__ wave, const float* __restrict__ win,
    const float* __restrict__ dftr, const float* __restrict__ dfti,
    const float* __restrict__ melw, float* __restrict__ out) {
    __shared__ float s_fr[TFB][PW];
    __shared__ float s_pw[TFB][NB + 1];
    const int tid = threadIdx.x, wv = tid >> 6, lane = tid & 63;
    const int fbase = blockIdx.x * TFB;
    #pragma unroll
    for (int j = 0; j < TFB / 4; ++j) {
        const int lf = wv * (TFB / 4) + j;
        const int gid = fbase + lf;
        const int bb = gid / NFRAMES;
        const int fr = gid - bb * NFRAMES;
        const float* x = wave + (size_t)bb * TLEN + (size_t)fr * FS;
        float s = 0.f;
        for (int i = lane; i < FL; i += 64) s += x[i];
        #pragma unroll
        for (int off = 32; off >= 1; off >>= 1) s += __shfl_xor(s, off);
        const float mean = s * (1.0f / FL);
        for (int i = lane; i < FL; i += 64) {
            const float xi = x[i];
            const float xm = (i == 0) ? xi : x[i - 1];
            s_fr[lf][i] = (xi - PRE * xm - (1.0f - PRE) * mean) * win[i];
        }
        for (int i = FL + lane; i < PW; i += 64) s_fr[lf][i] = 0.f;
    }
    __syncthreads();
    {
        const int bin = tid;
        const float4* dr4 = (const float4*)(dftr + (size_t)bin * PW);
        const float4* di4 = (const float4*)(dfti + (size_t)bin * PW);
        float accr[TFB], acci[TFB];
        #pragma unroll
        for (int f = 0; f < TFB; ++f) { accr[f] = 0.f; acci[f] = 0.f; }
        for (int k4 = 0; k4 < PW / 4; ++k4) {
            const float4 r = dr4[k4], im = di4[k4];
            #pragma unroll
            for (int f = 0; f < TFB; ++f) {
                const float4 fr = *(const float4*)&s_fr[f][k4 * 4];
                accr[f] += fr.x * r.x + fr.y * r.y + fr.z * r.z + fr.w * r.w;
                acci[f] += fr.x * im.x + fr.y * im.y + fr.z * im.z + fr.w * im.w;
            }
        }
        #pragma unroll
        for (int f = 0; f < TFB; ++f) s_pw[f][bin] = accr[f] * accr[f] + acci[f] * acci[f];
    }
    __syncthreads();
    for (int o = tid; o < TFB * NM; o += 256) {
        const int f = o / NM, m = o - f * NM;
        const float* wm = melw + (size_t)m * 257;
        float acc = 0.f;
        for (int k = 0; k < NB; ++k) acc += s_pw[f][k] * wm[k];
        out[(size_t)(fbase + f) * NM + m] = logf(fmaxf(acc + EPSF, EPSF));
    }
}

extern "C" void kernel_launch(void* const* d_in, const int* in_sizes, int n_in,
                              void* d_out, int out_size, void* d_ws, size_t ws_size,
                              hipStream_t stream) {
    const float* wave = (const float*)d_in[0];
    const float* win  = (const float*)d_in[1];
    const float* dftr = (const float*)d_in[2];
    const float* dfti = (const float*)d_in[3];
    const float* melw = (const float*)d_in[4];
    float* out = (float*)d_out;

    if (ws_size >= WS_NEED) {
        u16* wsb = (u16*)d_ws;
        const int prep_threads = MAIN_GROUPS + MEL_GROUPS;
        prep_kernel<<<(prep_threads + 255) / 256, 256, 0, stream>>>(dftr, dfti, melw, wsb);
        dim3 grid(NTILES, BATCH);
        fbank_mfma<<<grid, 256, 0, stream>>>(wave, win, wsb, out);
    } else {
        const int nblocks = (BATCH * NFRAMES) / TFB;
        fbank_fallback<<<nblocks, 256, 0, stream>>>(wave, win, dftr, dfti, melw, out);
    }
}

// Round 8
// 158.146 us; speedup vs baseline: 13.5078x; 1.0017x over previous
//
#include <hip/hip_runtime.h>
#include <math.h>

// Fbank via split-bf16 MFMA. R8: MT=64 frames/block (same 256 thr / 4 waves).
// Halves per-frame B-fragment L2 traffic (2.56 -> 1.28 GB) and doubles MFMA
// per B-load group (12 -> 24, ~240 cyc latency shadow with 2 waves/SIMD).
// acc = 128 AGPR -> __launch_bounds__(256,2): 256-reg budget, spill-free.

#define BATCH 32
#define TLEN 480000
#define NFRAMES 2998
#define FL 400
#define FS 160
#define PW 512
#define NM 80
#define MT 64                // frames per block
#define NTILES 47            // ceil(2998/64)
#define KS_MAIN 13           // k-steps of 32: covers k<416 (A zero for k>=400)
#define CH0 7                // chunk 0: ks 0..6   (cols 0..223)
#define CH1 6                // chunk 1: ks 7..12  (cols 224..415)
#define CCOL 224             // cols per chunk buffer
#define CROWB 448            // bytes per A row in chunk buffer
#define PRE 0.97f
#define EPSF 1e-6f

typedef short bf16x8 __attribute__((ext_vector_type(8)));
typedef float f32x4 __attribute__((ext_vector_type(4)));
typedef unsigned int u32;
typedef unsigned short u16;
typedef u32 u32x4 __attribute__((ext_vector_type(4)));

#define MAIN_GROUPS (32 * KS_MAIN * 64)   // fragment-groups (re+im x 13 ks)
#define MAIN_U16 (MAIN_GROUPS * 8)        // u16 per plane (hi, lo)
#define MEL_GROUPS (6 * 8 * 64)
#define MEL_U16 (MEL_GROUPS * 8)
#define WS_NEED ((size_t)(2 * MAIN_U16 + MEL_U16) * 2)   // ~901 KB

__device__ __forceinline__ u16 f2bf(float f) {
    u32 u = __builtin_bit_cast(u32, f);
    return (u16)((u + 0x7FFFu + ((u >> 16) & 1u)) >> 16);
}
__device__ __forceinline__ float bf2f(u16 h) {
    u32 u = ((u32)h) << 16;
    return __builtin_bit_cast(float, u);
}

// ---------------- prep: pack B (DFT re/im, hi+lo planes) + mel weights ----------------
__global__ void prep_kernel(const float* __restrict__ dftr, const float* __restrict__ dfti,
                            const float* __restrict__ melw, u16* __restrict__ wsb) {
    int idx = blockIdx.x * 256 + threadIdx.x;
    if (idx < MAIN_GROUPS) {
        int nf = idx / (KS_MAIN * 64);
        int rem = idx - nf * (KS_MAIN * 64);
        int ks = rem >> 6;
        int l  = rem & 63;
        int n  = nf * 16 + (l & 15);          // 0..511: re 0..255, im 256..511
        int k  = ks * 32 + ((l >> 4) << 3);   // < 416 <= 512
        const float* src = (n < 256) ? (dftr + (size_t)n * PW + k)
                                     : (dfti + (size_t)(n - 256) * PW + k);
        u16* dh = wsb + (size_t)idx * 8;
        u16* dl = wsb + (size_t)MAIN_U16 + (size_t)idx * 8;
        #pragma unroll
        for (int e = 0; e < 8; ++e) {
            float x = src[e];
            u16 h = f2bf(x);
            dh[e] = h;
            dl[e] = f2bf(x - bf2f(h));
        }
    } else {
        int j = idx - MAIN_GROUPS;
        if (j < MEL_GROUPS) {
            int nf = j / (8 * 64);
            int ks = (j >> 6) & 7;
            int l  = j & 63;
            int n  = nf * 16 + (l & 15);
            int k  = ks * 32 + ((l >> 4) << 3);
            u16* dst = wsb + (size_t)(2 * MAIN_U16) + (size_t)j * 8;
            if (n < NM) {
                const float* src = melw + (size_t)n * 257 + k;   // col 256 never read
                #pragma unroll
                for (int e = 0; e < 8; ++e) dst[e] = f2bf(src[e]);
            } else {
                #pragma unroll
                for (int e = 0; e < 8; ++e) dst[e] = 0;
            }
        }
    }
}

// A-chunk swizzle for 448-B stride: rows -> 4-bank-group rotation (2-way residual = free)
#define SWA(row) ((((u32)(row) >> 1) & 3u) << 4)

// 24 MFMA per B group: 4 m-frags x 6 split-product terms
#define MFMA24(BU, J)                                                                       \
    _Pragma("unroll")                                                                       \
    for (int mf = 0; mf < 4; ++mf) {                                                        \
        accR[mf][J] = __builtin_amdgcn_mfma_f32_16x16x32_bf16(aH[mf], BU[0], accR[mf][J], 0, 0, 0); \
        accR[mf][J] = __builtin_amdgcn_mfma_f32_16x16x32_bf16(aL[mf], BU[0], accR[mf][J], 0, 0, 0); \
        accR[mf][J] = __builtin_amdgcn_mfma_f32_16x16x32_bf16(aH[mf], BU[1], accR[mf][J], 0, 0, 0); \
        accI[mf][J] = __builtin_amdgcn_mfma_f32_16x16x32_bf16(aH[mf], BU[2], accI[mf][J], 0, 0, 0); \
        accI[mf][J] = __builtin_amdgcn_mfma_f32_16x16x32_bf16(aL[mf], BU[2], accI[mf][J], 0, 0, 0); \
        accI[mf][J] = __builtin_amdgcn_mfma_f32_16x16x32_bf16(aH[mf], BU[3], accI[mf][J], 0, 0, 0); \
    }

template<int KS0, int NKS>
__device__ __forceinline__ void dft_chunk(
    const u16* sAh, const u16* sAl,
    const u16* __restrict__ bh, const u16* __restrict__ bl,
    int g, int lane, f32x4 (&accR)[4][4], f32x4 (&accI)[4][4]) {

    bf16x8 aH[4], aL[4], BA[4], BB[4];

#define LDA_C(KS)                                                              \
    { _Pragma("unroll")                                                        \
      for (int mf = 0; mf < 4; ++mf) {                                         \
        u32 row_ = (u32)(mf * 16 + (lane & 15));                               \
        u32 koff_ = ((u32)((KS) * 64 + ((lane >> 4) << 4))) ^ SWA(row_);       \
        u32 byte_ = row_ * CROWB + koff_;                                      \
        aH[mf] = *(const bf16x8*)((const char*)sAh + byte_);                   \
        aL[mf] = *(const bf16x8*)((const char*)sAl + byte_);                   \
      } }
#define LDB_C(KSG, J, D)                                                       \
    {                                                                          \
        const int nfR_ = 4 * g + (J), nfI_ = 16 + 4 * g + (J);                 \
        const size_t oR_ = ((size_t)(nfR_ * KS_MAIN + (KSG)) * 64 + lane) * 8; \
        const size_t oI_ = ((size_t)(nfI_ * KS_MAIN + (KSG)) * 64 + lane) * 8; \
        D[0] = *(const bf16x8*)(bh + oR_);                                     \
        D[1] = *(const bf16x8*)(bl + oR_);                                     \
        D[2] = *(const bf16x8*)(bh + oI_);                                     \
        D[3] = *(const bf16x8*)(bl + oI_);                                     \
    }

    LDB_C(KS0, 0, BA);
    for (int ks = 0; ks < NKS; ++ks) {
        LDA_C(ks);
        LDB_C(KS0 + ks, 1, BB);
        MFMA24(BA, 0);
        LDB_C(KS0 + ks, 2, BA);
        MFMA24(BB, 1);
        LDB_C(KS0 + ks, 3, BB);
        MFMA24(BA, 2);
        if (ks + 1 < NKS) LDB_C(KS0 + ks + 1, 0, BA);
        MFMA24(BB, 3);
    }
#undef LDA_C
#undef LDB_C
}

// ---------------- main fused kernel ----------------
__global__ __launch_bounds__(256, 2) void fbank_mfma(
    const float* __restrict__ wave, const float* __restrict__ win,
    const u16* __restrict__ wsb, float* __restrict__ out) {
    __shared__ u16 sbuf[MT * CCOL * 2];          // 57,344 B (hi plane then lo plane)
    u16* sAh = sbuf;
    u16* sAl = sbuf + MT * CCOL;

    const int tid = threadIdx.x, w = tid >> 6, lane = tid & 63;
    const int b = blockIdx.y;
    const int f0 = blockIdx.x * MT;
    const float* wb = wave + (size_t)b * TLEN;
    const float4* win4 = (const float4*)win;

    const int h  = lane >> 5;      // frame half (2 frames per step)
    const int gg = lane & 31;      // group within half

    // ---- Phase 1a: means (8 steps x 2 frames per wave = 16 frames/wave) ----
    float mean[8];
    #pragma unroll
    for (int s = 0; s < 8; ++s) {
        const int fr = f0 + w * 16 + 2 * s + h;
        float acc = 0.f;
        if (fr < NFRAMES) {
            const float4* x4 = (const float4*)(wb + (size_t)fr * FS);
            float4 a = x4[gg], c = x4[gg + 32], d = x4[gg + 64];
            acc = a.x + a.y + a.z + a.w + c.x + c.y + c.z + c.w + d.x + d.y + d.z + d.w;
            if (gg < 4) { float4 e = x4[gg + 96]; acc += e.x + e.y + e.z + e.w; }
        }
        #pragma unroll
        for (int o = 16; o; o >>= 1) acc += __shfl_xor(acc, o);
        mean[s] = acc * (1.0f / FL);
    }

    // ---- Phase 1b: window+preemph chunk 0 (samples 0..223), write swizzled ----
    #pragma unroll
    for (int s = 0; s < 8; ++s) {
        const int rr = w * 16 + 2 * s + h;
        const int fr = f0 + rr;
        const bool valid = fr < NFRAMES;
        const float* x = wb + (size_t)fr * FS;
        const float4* x4 = (const float4*)x;
        if (gg < 28) {
            float4 v0 = {0,0,0,0}, v1 = {0,0,0,0};
            if (valid) { v0 = x4[2 * gg]; v1 = x4[2 * gg + 1]; }
            float4 w0 = win4[2 * gg], w1 = win4[2 * gg + 1];
            float xpn = __shfl(v1.w, lane - 1);
            float xprev = (gg == 0) ? v0.x : xpn;
            const float mc = (1.0f - PRE) * mean[s];
            float ys[8];
            ys[0] = (v0.x - PRE * xprev - mc) * w0.x;
            ys[1] = (v0.y - PRE * v0.x - mc) * w0.y;
            ys[2] = (v0.z - PRE * v0.y - mc) * w0.z;
            ys[3] = (v0.w - PRE * v0.z - mc) * w0.w;
            ys[4] = (v1.x - PRE * v0.w - mc) * w1.x;
            ys[5] = (v1.y - PRE * v1.x - mc) * w1.y;
            ys[6] = (v1.z - PRE * v1.y - mc) * w1.z;
            ys[7] = (v1.w - PRE * v1.z - mc) * w1.w;
            u32x4 hv, lv;
            #pragma unroll
            for (int e = 0; e < 4; ++e) {
                u16 h0 = f2bf(ys[2 * e]), h1 = f2bf(ys[2 * e + 1]);
                hv[e] = (u32)h0 | ((u32)h1 << 16);
                u16 l0 = f2bf(ys[2 * e] - bf2f(h0)), l1 = f2bf(ys[2 * e + 1] - bf2f(h1));
                lv[e] = (u32)l0 | ((u32)l1 << 16);
            }
            u32 byte = (u32)rr * CROWB + (((u32)gg * 16u) ^ SWA(rr));
            *(u32x4*)((char*)sAh + byte) = hv;
            *(u32x4*)((char*)sAl + byte) = lv;
        }
    }
    __syncthreads();

    // ---- Phase 2a: DFT GEMM chunk 0 (ks 0..6); wave g owns bins 64g..64g+63 ----
    const int g = w;
    f32x4 accR[4][4], accI[4][4];
    #pragma unroll
    for (int mf = 0; mf < 4; ++mf)
        #pragma unroll
        for (int j = 0; j < 4; ++j) { accR[mf][j] = (f32x4)0.f; accI[mf][j] = (f32x4)0.f; }

    dft_chunk<0, CH0>(sAh, sAl, wsb, wsb + MAIN_U16, g, lane, accR, accI);
    __syncthreads();

    // ---- Phase 1c: window+preemph chunk 1 (samples 224..415; >=400 zero) ----
    #pragma unroll
    for (int s = 0; s < 8; ++s) {
        const int rr = w * 16 + 2 * s + h;
        const int fr = f0 + rr;
        const bool valid = fr < NFRAMES;
        const float* x = wb + (size_t)fr * FS;
        const float4* x4 = (const float4*)x;
        if (gg < 24) {
            float4 v0 = {0,0,0,0}, v1 = {0,0,0,0}, w0 = {0,0,0,0}, w1 = {0,0,0,0};
            const bool live = gg < 22;                       // samples < 400
            if (live) {
                if (valid) { v0 = x4[56 + 2 * gg]; v1 = x4[57 + 2 * gg]; }
                w0 = win4[56 + 2 * gg]; w1 = win4[57 + 2 * gg];
            }
            float xpn = __shfl(v1.w, lane - 1);
            float xprev = xpn;
            if (gg == 0) xprev = valid ? x[223] : 0.f;
            const float mc = (1.0f - PRE) * mean[s];
            float ys[8];
            if (live) {
                ys[0] = (v0.x - PRE * xprev - mc) * w0.x;
                ys[1] = (v0.y - PRE * v0.x - mc) * w0.y;
                ys[2] = (v0.z - PRE * v0.y - mc) * w0.z;
                ys[3] = (v0.w - PRE * v0.z - mc) * w0.w;
                ys[4] = (v1.x - PRE * v0.w - mc) * w1.x;
                ys[5] = (v1.y - PRE * v1.x - mc) * w1.y;
                ys[6] = (v1.z - PRE * v1.y - mc) * w1.z;
                ys[7] = (v1.w - PRE * v1.z - mc) * w1.w;
            } else {
                #pragma unroll
                for (int e = 0; e < 8; ++e) ys[e] = 0.f;
            }
            u32x4 hv, lv;
            #pragma unroll
            for (int e = 0; e < 4; ++e) {
                u16 h0 = f2bf(ys[2 * e]), h1 = f2bf(ys[2 * e + 1]);
                hv[e] = (u32)h0 | ((u32)h1 << 16);
                u16 l0 = f2bf(ys[2 * e] - bf2f(h0)), l1 = f2bf(ys[2 * e + 1] - bf2f(h1));
                lv[e] = (u32)l0 | ((u32)l1 << 16);
            }
            u32 byte = (u32)rr * CROWB + (((u32)gg * 16u) ^ SWA(rr));
            *(u32x4*)((char*)sAh + byte) = hv;
            *(u32x4*)((char*)sAl + byte) = lv;
        }
    }
    __syncthreads();

    // ---- Phase 2b: DFT GEMM chunk 1 (ks 7..12) ----
    dft_chunk<CH0, CH1>(sAh, sAl, wsb, wsb + MAIN_U16, g, lane, accR, accI);
    __syncthreads();

    // ---- Phase 3: power -> LDS bf16 [64][256] overlaying sbuf (512-B stride) ----
    #pragma unroll
    for (int mf = 0; mf < 4; ++mf)
        #pragma unroll
        for (int j = 0; j < 4; ++j)
            #pragma unroll
            for (int r = 0; r < 4; ++r) {
                float pR = accR[mf][j][r], pI = accI[mf][j][r];
                float pw = pR * pR + pI * pI;
                u32 row = (u32)(mf * 16 + ((lane >> 4) << 2) + r);
                u32 bin = (u32)(64 * g + j * 16 + (lane & 15));
                u32 byte = (row * 512u + bin * 2u) ^ ((row & 7) << 4);
                *(u16*)((char*)sbuf + byte) = f2bf(pw);
            }
    __syncthreads();

    // ---- Phase 4: mel GEMM (M=64, N=96 padded, K=256) + log epilogue ----
    const u16* melb = wsb + (size_t)(2 * MAIN_U16);
    #pragma unroll
    for (int cc = 0; cc < 2; ++cc) {
        const int combo = w * 2 + cc;          // 0..7
        const int mfm = combo >> 1;            // 0..3: rows mfm*16..+15
        const int nf0 = (combo & 1) ? 3 : 0;   // frag trio {0,1,2} or {3,4,5(pad)}
        f32x4 accM[3];
        #pragma unroll
        for (int j = 0; j < 3; ++j) accM[j] = (f32x4)0.f;

        for (int ks = 0; ks < 8; ++ks) {
            u32 row = (u32)(mfm * 16 + (lane & 15));
            u32 byte = (row * 512u + (u32)(ks * 32 + ((lane >> 4) << 3)) * 2u) ^ ((row & 7) << 4);
            bf16x8 aP = *(const bf16x8*)((const char*)sbuf + byte);
            #pragma unroll
            for (int j = 0; j < 3; ++j) {
                bf16x8 bM = *(const bf16x8*)(melb + ((size_t)((nf0 + j) * 8 + ks) * 64 + lane) * 8);
                accM[j] = __builtin_amdgcn_mfma_f32_16x16x32_bf16(aP, bM, accM[j], 0, 0, 0);
            }
        }
        #pragma unroll
        for (int j = 0; j < 3; ++j) {
            const int m = (nf0 + j) * 16 + (lane & 15);
            #pragma unroll
            for (int r = 0; r < 4; ++r) {
                const int rowl = mfm * 16 + ((lane >> 4) << 2) + r;
                const int fr = f0 + rowl;
                if (fr < NFRAMES && m < NM) {
                    float v = fmaxf(accM[j][r] + EPSF, EPSF);
                    out[((size_t)b * NFRAMES + fr) * NM + m] = logf(v);
                }
            }
        }
    }
}

// ---------------- fallback (round-1 fp32 kernel, used if ws too small) ----------------
#define TFB 16
#define NB 256
__global__ __launch_bounds__(256, 3) void fbank_fallback(
    const float* __restrict__ wave, const float* __restrict__ win,
    const float* __restrict__ dftr, const float* __restrict__ dfti,
    const float* __restrict__ melw, float* __restrict__ out) {
    __shared__ float s_fr[TFB][PW];
    __shared__ float s_pw[TFB][NB + 1];
    const int tid = threadIdx.x, wv = tid >> 6, lane = tid & 63;
    const int fbase = blockIdx.x * TFB;
    #pragma unroll
    for (int j = 0; j < TFB / 4; ++j) {
        const int lf = wv * (TFB / 4) + j;
        const int gid = fbase + lf;
        const int bb = gid / NFRAMES;
        const int fr = gid - bb * NFRAMES;
        const float* x = wave + (size_t)bb * TLEN + (size_t)fr * FS;
        float s = 0.f;
        for (int i = lane; i < FL; i += 64) s += x[i];
        #pragma unroll
        for (int off = 32; off >= 1; off >>= 1) s += __shfl_xor(s, off);
        const float mean = s * (1.0f / FL);
        for (int i = lane; i < FL; i += 64) {
            const float xi = x[i];
            const float xm = (i == 0) ? xi : x[i - 1];
            s_fr[lf][i] = (xi - PRE * xm - (1.0f - PRE) * mean) * win[i];
        }
        for (int i = FL + lane; i < PW; i += 64) s_fr[lf][i] = 0.f;
    }
    __syncthreads();
    {
        const int bin = tid;
        const float4* dr4 = (const float4*)(dftr + (size_t)bin * PW);
        const float4* di4 = (const float4*)(dfti + (size_t)bin * PW);
        float accr[TFB], acci[TFB];
        #pragma unroll
        for (int f = 0; f < TFB; ++f) { accr[f] = 0.f; acci[f] = 0.f; }
        for (int k4 = 0; k4 < PW / 4; ++k4) {
            const float4 r = dr4[k4], im = di4[k4];
            #pragma unroll
            for (int f = 0; f < TFB; ++f) {
                const float4 fr = *(const float4*)&s_fr[f][k4 * 4];
                accr[f] += fr.x * r.x + fr.y * r.y + fr.z * r.z + fr.w * r.w;
                acci[f] += fr.x * im.x + fr.y * im.y + fr.z * im.z + fr.w * im.w;
            }
        }
        #pragma unroll
        for (int f = 0; f < TFB; ++f) s_pw[f][bin] = accr[f] * accr[f] + acci[f] * acci[f];
    }
    __syncthreads();
    for (int o = tid; o < TFB * NM; o += 256) {
        const int f = o / NM, m = o - f * NM;
        const float* wm = melw + (size_t)m * 257;
        float acc = 0.f;
        for (int k = 0; k < NB; ++k) acc += s_pw[f][k] * wm[k];
        out[(size_t)(fbase + f) * NM + m] = logf(fmaxf(acc + EPSF, EPSF));
    }
}

extern "C" void kernel_launch(void* const* d_in, const int* in_sizes, int n_in,
                              void* d_out, int out_size, void* d_ws, size_t ws_size,
                              hipStream_t stream) {
    const float* wave = (const float*)d_in[0];
    const float* win  = (const float*)d_in[1];
    const float* dftr = (const float*)d_in[2];
    const float* dfti = (const float*)d_in[3];
    const float* melw = (const float*)d_in[4];
    float* out = (float*)d_out;

    if (ws_size >= WS_NEED) {
        u16* wsb = (u16*)d_ws;
        const int prep_threads = MAIN_GROUPS + MEL_GROUPS;
        prep_kernel<<<(prep_threads + 255) / 256, 256, 0, stream>>>(dftr, dfti, melw, wsb);
        dim3 grid(NTILES, BATCH);
        fbank_mfma<<<grid, 256, 0, stream>>>(wave, win, wsb, out);
    } else {
        const int nblocks = (BATCH * NFRAMES) / TFB;
        fbank_fallback<<<nblocks, 256, 0, stream>>>(wave, win, dftr, dfti, melw, out);
    }
}

// Round 9
// 133.899 us; speedup vs baseline: 15.9539x; 1.1811x over previous
//
#include <hip/hip_runtime.h>
#include <math.h>

// Fbank via split-bf16 MFMA + real-DFT symmetry folding (R9).
// real[f] = sum_{t=0..256} s[t] cos(2pi f t/512),  s[t]=y[t]+y[512-t]
// imag[f] = sum_{t=0..255} d[t] (-sin(...)),       d[t]=y[t]-y[512-t]
// -> 0.65x MFMA work, 0.64x B-fragment L2 traffic vs unfolded K=416.
// Two K-chunks (t 0..127, 128..287); s,d tiles built in one pass per chunk.

#define BATCH 32
#define TLEN 480000
#define NFRAMES 2998
#define FL 400
#define FS 160
#define PW 512
#define NM 80
#define MT 64                // frames per block
#define NTILES 47            // ceil(2998/64)
#define PRE 0.97f
#define EPSF 1e-6f

#define RE_KS 9              // K=288 (t 0..256 + pad)
#define IM_KS 8              // K=256 (t 0..255)
#define RE_U16 (16 * RE_KS * 64 * 8)   // 73728
#define IM_U16 (16 * IM_KS * 64 * 8)   // 65536
#define MEL_U16 (6 * 8 * 64 * 8)       // 24576
#define OFF_REH 0
#define OFF_REL RE_U16
#define OFF_IMH (2 * RE_U16)
#define OFF_IML (2 * RE_U16 + IM_U16)
#define OFF_MEL (2 * RE_U16 + 2 * IM_U16)
#define WS_NEED ((size_t)(OFF_MEL + MEL_U16) * 2)   // 606,208 B

// LDS tile byte offsets (within 73728-B tile buffer)
#define C0_SH 0
#define C0_SL 16384
#define C0_DH 32768
#define C0_DL 49152
#define C1_SH 0
#define C1_SL 20480
#define C1_DH 40960
#define C1_DL 57344

typedef short bf16x8 __attribute__((ext_vector_type(8)));
typedef float f32x4 __attribute__((ext_vector_type(4)));
typedef unsigned int u32;
typedef unsigned short u16;
typedef u32 u32x4 __attribute__((ext_vector_type(4)));

__device__ __forceinline__ u16 f2bf(float f) {
    u32 u = __builtin_bit_cast(u32, f);
    return (u16)((u + 0x7FFFu + ((u >> 16) & 1u)) >> 16);
}
__device__ __forceinline__ float bf2f(u16 h) {
    u32 u = ((u32)h) << 16;
    return __builtin_bit_cast(float, u);
}

// ---------------- prep: pack folded B (cos K=288, sin K=256, hi+lo) + mel ----------------
__global__ void prep_kernel(const float* __restrict__ dftr, const float* __restrict__ dfti,
                            const float* __restrict__ melw, u16* __restrict__ wsb) {
    int idx = blockIdx.x * 256 + threadIdx.x;
    if (idx < 16 * RE_KS * 64) {                       // 9216 Re groups
        int nf = idx / (RE_KS * 64);
        int rem = idx - nf * (RE_KS * 64);
        int ks = rem >> 6, l = rem & 63;
        int f = nf * 16 + (l & 15);
        int k = ks * 32 + ((l >> 4) << 3);
        u16* dh = wsb + OFF_REH + (size_t)idx * 8;
        u16* dl = wsb + OFF_REL + (size_t)idx * 8;
        #pragma unroll
        for (int e = 0; e < 8; ++e) {
            int kk = k + e;
            float x = (kk <= 256) ? dftr[(size_t)f * PW + kk] : 0.f;
            u16 h = f2bf(x);
            dh[e] = h;
            dl[e] = f2bf(x - bf2f(h));
        }
    } else if (idx < 16 * RE_KS * 64 + 16 * IM_KS * 64) {   // 8192 Im groups
        int j = idx - 16 * RE_KS * 64;
        int nf = j / (IM_KS * 64);
        int rem = j - nf * (IM_KS * 64);
        int ks = rem >> 6, l = rem & 63;
        int f = nf * 16 + (l & 15);
        int k = ks * 32 + ((l >> 4) << 3);
        u16* dh = wsb + OFF_IMH + (size_t)j * 8;
        u16* dl = wsb + OFF_IML + (size_t)j * 8;
        #pragma unroll
        for (int e = 0; e < 8; ++e) {
            float x = dfti[(size_t)f * PW + k + e];    // k+e <= 255
            u16 h = f2bf(x);
            dh[e] = h;
            dl[e] = f2bf(x - bf2f(h));
        }
    } else {                                            // 3072 mel groups
        int m = idx - (16 * RE_KS * 64 + 16 * IM_KS * 64);
        if (m < 6 * 8 * 64) {
            int nf = m / (8 * 64);
            int ks = (m >> 6) & 7, l = m & 63;
            int n = nf * 16 + (l & 15);
            int k = ks * 32 + ((l >> 4) << 3);
            u16* dst = wsb + OFF_MEL + (size_t)m * 8;
            #pragma unroll
            for (int e = 0; e < 8; ++e)
                dst[e] = (n < NM) ? f2bf(melw[(size_t)n * 257 + k + e]) : (u16)0;
        }
    }
}

// ---------------- DFT pass: 3-term split product over one A-tile chunk ----------------
template<int RS, int SWT, int NKS, int BKS>
__device__ __forceinline__ void dft_pass(
    const char* tH, const char* tL,
    const u16* __restrict__ bH, const u16* __restrict__ bL,
    int ks0, int g, int lane, f32x4 (&acc)[4][4]) {
    #pragma unroll
    for (int ks = 0; ks < NKS; ++ks) {
        bf16x8 aH[4], aL[4];
        #pragma unroll
        for (int mf = 0; mf < 4; ++mf) {
            u32 r = (u32)(mf * 16 + (lane & 15));
            u32 off = (u32)(ks * 64 + ((lane >> 4) << 4));
            u32 sw = (SWT == 0) ? ((r & 7u) << 4) : (((r >> 1) & 3u) << 4);
            u32 byte = r * RS + (off ^ sw);
            aH[mf] = *(const bf16x8*)(tH + byte);
            aL[mf] = *(const bf16x8*)(tL + byte);
        }
        #pragma unroll
        for (int j = 0; j < 4; ++j) {
            size_t o = ((size_t)((4 * g + j) * BKS + ks0 + ks) * 64 + lane) * 8;
            bf16x8 bh = *(const bf16x8*)(bH + o);
            bf16x8 bl = *(const bf16x8*)(bL + o);
            #pragma unroll
            for (int mf = 0; mf < 4; ++mf) {
                acc[mf][j] = __builtin_amdgcn_mfma_f32_16x16x32_bf16(aH[mf], bh, acc[mf][j], 0, 0, 0);
                acc[mf][j] = __builtin_amdgcn_mfma_f32_16x16x32_bf16(aL[mf], bh, acc[mf][j], 0, 0, 0);
                acc[mf][j] = __builtin_amdgcn_mfma_f32_16x16x32_bf16(aH[mf], bl, acc[mf][j], 0, 0, 0);
            }
        }
    }
}

__device__ __forceinline__ void pack_write(const float* ys, char* baseH, char* baseL, u32 byte) {
    u32x4 hv, lv;
    #pragma unroll
    for (int e = 0; e < 4; ++e) {
        u16 h0 = f2bf(ys[2 * e]), h1 = f2bf(ys[2 * e + 1]);
        hv[e] = (u32)h0 | ((u32)h1 << 16);
        u16 l0 = f2bf(ys[2 * e] - bf2f(h0)), l1 = f2bf(ys[2 * e + 1] - bf2f(h1));
        lv[e] = (u32)l0 | ((u32)l1 << 16);
    }
    *(u32x4*)(baseH + byte) = hv;
    *(u32x4*)(baseL + byte) = lv;
}

// ---------------- main fused kernel ----------------
__global__ __launch_bounds__(256, 2) void fbank_mfma(
    const float* __restrict__ wave, const float* __restrict__ win,
    const u16* __restrict__ wsb, float* __restrict__ out) {
    __shared__ float smean[64];
    __shared__ u16 stile[36864];       // 73,728 B tile buffer
    char* T = (char*)stile;

    const int tid = threadIdx.x, w = tid >> 6, lane = tid & 63;
    const int q = lane >> 4;           // frame quarter within step
    const int cg = lane & 15;          // col-group
    const int b = blockIdx.y;
    const int f0 = blockIdx.x * MT;
    const float* wb = wave + (size_t)b * TLEN;
    const float4* win4 = (const float4*)win;

    // ---- means -> LDS ----
    #pragma unroll
    for (int i = 0; i < 4; ++i) {
        const int rr = w * 16 + i * 4 + q;
        const int fr = f0 + rr;
        float acc = 0.f;
        if (fr < NFRAMES) {
            const float4* x4 = (const float4*)(wb + (size_t)fr * FS);
            #pragma unroll
            for (int m = 0; m < 6; ++m) {
                float4 a = x4[cg + 16 * m];
                acc += a.x + a.y + a.z + a.w;
            }
            if (cg < 4) { float4 a = x4[96 + cg]; acc += a.x + a.y + a.z + a.w; }
        }
        #pragma unroll
        for (int o = 8; o; o >>= 1) acc += __shfl_xor(acc, o);
        if (cg == 0) smean[rr] = acc * (1.0f / FL);
    }
    __syncthreads();

    // ---- P1b: chunk0 (t 0..127): build s,d tiles ----
    #pragma unroll
    for (int i = 0; i < 4; ++i) {
        const int rr = w * 16 + i * 4 + q;
        const int fr = f0 + rr;
        const bool valid = fr < NFRAMES;
        const float* x = wb + (size_t)fr * FS;
        const float4* x4 = (const float4*)x;
        const float mc = (1.0f - PRE) * smean[rr];

        float4 v0 = {0,0,0,0}, v1 = {0,0,0,0};
        if (valid) { v0 = x4[2 * cg]; v1 = x4[2 * cg + 1]; }
        float4 w0 = win4[2 * cg], w1 = win4[2 * cg + 1];
        float xpn = __shfl(v1.w, lane - 1);
        float xprev = (cg == 0) ? v0.x : xpn;
        float y[8];
        y[0] = (v0.x - PRE * xprev - mc) * w0.x;
        y[1] = (v0.y - PRE * v0.x - mc) * w0.y;
        y[2] = (v0.z - PRE * v0.y - mc) * w0.z;
        y[3] = (v0.w - PRE * v0.z - mc) * w0.w;
        y[4] = (v1.x - PRE * v0.w - mc) * w1.x;
        y[5] = (v1.y - PRE * v1.x - mc) * w1.y;
        y[6] = (v1.z - PRE * v1.y - mc) * w1.z;
        y[7] = (v1.w - PRE * v1.z - mc) * w1.w;

        float yr[8];
        #pragma unroll
        for (int e = 0; e < 8; ++e) yr[e] = 0.f;
        if (cg >= 14) {                      // t >= 113 folds (u = 512-t in 385..399)
            const int u0 = 512 - 8 * cg;     // 400 (cg14) or 392 (cg15)
            float4 xr0 = {0,0,0,0}, xr1 = {0,0,0,0};
            float xu0 = 0.f;
            if (valid) {
                xr0 = x4[u0 / 4 - 2]; xr1 = x4[u0 / 4 - 1];
                if (u0 <= 399) xu0 = x[u0];
            }
            float4 wr0 = win4[u0 / 4 - 2], wr1 = win4[u0 / 4 - 1];
            float wu0 = (u0 <= 399) ? win[u0] : 0.f;
            yr[0] = (xu0   - PRE * xr1.w - mc) * wu0;
            yr[1] = (xr1.w - PRE * xr1.z - mc) * wr1.w;
            yr[2] = (xr1.z - PRE * xr1.y - mc) * wr1.z;
            yr[3] = (xr1.y - PRE * xr1.x - mc) * wr1.y;
            yr[4] = (xr1.x - PRE * xr0.w - mc) * wr1.x;
            yr[5] = (xr0.w - PRE * xr0.z - mc) * wr0.w;
            yr[6] = (xr0.z - PRE * xr0.y - mc) * wr0.z;
            yr[7] = (xr0.y - PRE * xr0.x - mc) * wr0.y;
        }
        float s8[8], d8[8];
        #pragma unroll
        for (int e = 0; e < 8; ++e) { s8[e] = y[e] + yr[e]; d8[e] = y[e] - yr[e]; }
        u32 byte = (u32)rr * 256u + (((u32)cg * 16u) ^ (((u32)rr & 7u) << 4));
        pack_write(s8, T + C0_SH, T + C0_SL, byte);
        pack_write(d8, T + C0_DH, T + C0_DL, byte);
    }
    __syncthreads();

    // ---- GEMM chunk0: Re ks 0..3 (A=s), Im ks 0..3 (A=d) ----
    const int g = w;
    f32x4 accR[4][4], accI[4][4];
    #pragma unroll
    for (int mf = 0; mf < 4; ++mf)
        #pragma unroll
        for (int j = 0; j < 4; ++j) { accR[mf][j] = (f32x4)0.f; accI[mf][j] = (f32x4)0.f; }

    dft_pass<256, 0, 4, RE_KS>(T + C0_SH, T + C0_SL, wsb + OFF_REH, wsb + OFF_REL, 0, g, lane, accR);
    dft_pass<256, 0, 4, IM_KS>(T + C0_DH, T + C0_DL, wsb + OFF_IMH, wsb + OFF_IML, 0, g, lane, accI);
    __syncthreads();

    // ---- P1c: chunk1 (t 128..255 fold; s also t 256..287 tail) ----
    #pragma unroll
    for (int i = 0; i < 4; ++i) {
        const int rr = w * 16 + i * 4 + q;
        const int fr = f0 + rr;
        const bool valid = fr < NFRAMES;
        const float* x = wb + (size_t)fr * FS;
        const float4* x4 = (const float4*)x;
        const float mc = (1.0f - PRE) * smean[rr];

        float4 v0 = {0,0,0,0}, v1 = {0,0,0,0};
        if (valid) { v0 = x4[32 + 2 * cg]; v1 = x4[33 + 2 * cg]; }
        float4 w0 = win4[32 + 2 * cg], w1 = win4[33 + 2 * cg];
        float xpn = __shfl(v1.w, lane - 1);
        float xprev = (cg == 0) ? (valid ? x[127] : 0.f) : xpn;
        float y[8];
        y[0] = (v0.x - PRE * xprev - mc) * w0.x;
        y[1] = (v0.y - PRE * v0.x - mc) * w0.y;
        y[2] = (v0.z - PRE * v0.y - mc) * w0.z;
        y[3] = (v0.w - PRE * v0.z - mc) * w0.w;
        y[4] = (v1.x - PRE * v0.w - mc) * w1.x;
        y[5] = (v1.y - PRE * v1.x - mc) * w1.y;
        y[6] = (v1.z - PRE * v1.y - mc) * w1.z;
        y[7] = (v1.w - PRE * v1.z - mc) * w1.w;

        const int u0 = 384 - 8 * cg;        // 264..384, all fold
        float4 xr0 = {0,0,0,0}, xr1 = {0,0,0,0};
        float xu0 = 0.f;
        if (valid) { xr0 = x4[u0 / 4 - 2]; xr1 = x4[u0 / 4 - 1]; xu0 = x[u0]; }
        float4 wr0 = win4[u0 / 4 - 2], wr1 = win4[u0 / 4 - 1];
        float wu0 = win[u0];
        float yr[8];
        yr[0] = (xu0   - PRE * xr1.w - mc) * wu0;
        yr[1] = (xr1.w - PRE * xr1.z - mc) * wr1.w;
        yr[2] = (xr1.z - PRE * xr1.y - mc) * wr1.z;
        yr[3] = (xr1.y - PRE * xr1.x - mc) * wr1.y;
        yr[4] = (xr1.x - PRE * xr0.w - mc) * wr1.x;
        yr[5] = (xr0.w - PRE * xr0.z - mc) * wr0.w;
        yr[6] = (xr0.z - PRE * xr0.y - mc) * wr0.z;
        yr[7] = (xr0.y - PRE * xr0.x - mc) * wr0.y;

        float s8[8], d8[8];
        #pragma unroll
        for (int e = 0; e < 8; ++e) { s8[e] = y[e] + yr[e]; d8[e] = y[e] - yr[e]; }
        u32 byteS = (u32)rr * 320u + (((u32)cg * 16u) ^ ((((u32)rr >> 1) & 3u) << 4));
        u32 byteD = (u32)rr * 256u + (((u32)cg * 16u) ^ (((u32)rr & 7u) << 4));
        pack_write(s8, T + C1_SH, T + C1_SL, byteS);
        pack_write(d8, T + C1_DH, T + C1_DL, byteD);
    }
    // s tail: cols t=256..287 (units 16..19): only t=256 nonzero
    {
        const int rr = tid & 63;
        const int grp = tid >> 6;          // 0..3 -> unit 16+grp
        const int fr = f0 + rr;
        float y256 = 0.f;
        if (grp == 0 && fr < NFRAMES) {
            const float* x = wb + (size_t)fr * FS;
            y256 = (x[256] - PRE * x[255] - (1.0f - PRE) * smean[rr]) * win[256];
        }
        float s8[8] = {y256, 0.f, 0.f, 0.f, 0.f, 0.f, 0.f, 0.f};
        u32 byte = (u32)rr * 320u + ((((u32)(16 + grp)) * 16u) ^ ((((u32)rr >> 1) & 3u) << 4));
        pack_write(s8, T + C1_SH, T + C1_SL, byte);
    }
    __syncthreads();

    // ---- GEMM chunk1: Re ks 4..8 (5 ks, A=s RS320), Im ks 4..7 (A=d RS256) ----
    dft_pass<320, 1, 5, RE_KS>(T + C1_SH, T + C1_SL, wsb + OFF_REH, wsb + OFF_REL, 4, g, lane, accR);
    dft_pass<256, 0, 4, IM_KS>(T + C1_DH, T + C1_DL, wsb + OFF_IMH, wsb + OFF_IML, 4, g, lane, accI);
    __syncthreads();

    // ---- power -> LDS bf16 [64][256] (512-B stride) ----
    #pragma unroll
    for (int mf = 0; mf < 4; ++mf)
        #pragma unroll
        for (int j = 0; j < 4; ++j)
            #pragma unroll
            for (int r = 0; r < 4; ++r) {
                float pR = accR[mf][j][r], pI = accI[mf][j][r];
                float pw = pR * pR + pI * pI;
                u32 row = (u32)(mf * 16 + (q << 2) + r);
                u32 bin = (u32)(64 * g + j * 16 + cg);
                u32 byte = (row * 512u + bin * 2u) ^ ((row & 7u) << 4);
                *(u16*)(T + byte) = f2bf(pw);
            }
    __syncthreads();

    // ---- mel GEMM (M=64, N=96 padded, K=256) + log epilogue ----
    const u16* melb = wsb + OFF_MEL;
    #pragma unroll
    for (int cc = 0; cc < 2; ++cc) {
        const int combo = w * 2 + cc;
        const int mfm = combo >> 1;
        const int nf0 = (combo & 1) ? 3 : 0;
        f32x4 accM[3];
        #pragma unroll
        for (int j = 0; j < 3; ++j) accM[j] = (f32x4)0.f;
        for (int ks = 0; ks < 8; ++ks) {
            u32 row = (u32)(mfm * 16 + cg);
            u32 byte = (row * 512u + (u32)(ks * 32 + (q << 3)) * 2u) ^ ((row & 7u) << 4);
            bf16x8 aP = *(const bf16x8*)(T + byte);
            #pragma unroll
            for (int j = 0; j < 3; ++j) {
                bf16x8 bM = *(const bf16x8*)(melb + ((size_t)((nf0 + j) * 8 + ks) * 64 + lane) * 8);
                accM[j] = __builtin_amdgcn_mfma_f32_16x16x32_bf16(aP, bM, accM[j], 0, 0, 0);
            }
        }
        #pragma unroll
        for (int j = 0; j < 3; ++j) {
            const int m = (nf0 + j) * 16 + cg;
            #pragma unroll
            for (int r = 0; r < 4; ++r) {
                const int rowl = mfm * 16 + (q << 2) + r;
                const int fr = f0 + rowl;
                if (fr < NFRAMES && m < NM) {
                    float v = fmaxf(accM[j][r] + EPSF, EPSF);
                    out[((size_t)b * NFRAMES + fr) * NM + m] = logf(v);
                }
            }
        }
    }
}

// ---------------- fallback (fp32 kernel, used if ws too small) ----------------
#define TFB 16
#define NB 256
__global__ __launch_bounds__(256, 3) void fbank_fallback(
    const float* __restrict__ wave, const float* __restrict__ win,
    const float* __restrict__ dftr, const float* __restrict__ dfti,
    const float* __restrict__ melw, float* __restrict__ out) {
    __shared__ float s_fr[TFB][PW];
    __shared__ float s_pw[TFB][NB + 1];
    const int tid = threadIdx.x, wv = tid >> 6, lane = tid & 63;
    const int fbase = blockIdx.x * TFB;
    #pragma unroll
    for (int j = 0; j < TFB / 4; ++j) {
        const int lf = wv * (TFB / 4) + j;
        const int gid = fbase + lf;
        const int bb = gid / NFRAMES;
        const int fr = gid - bb * NFRAMES;
        const float* x = wave + (size_t)bb * TLEN + (size_t)fr * FS;
        float s = 0.f;
        for (int i = lane; i < FL; i += 64) s += x[i];
        #pragma unroll
        for (int off = 32; off >= 1; off >>= 1) s += __shfl_xor(s, off);
        const float mean = s * (1.0f / FL);
        for (int i = lane; i < FL; i += 64) {
            const float xi = x[i];
            const float xm = (i == 0) ? xi : x[i - 1];
            s_fr[lf][i] = (xi - PRE * xm - (1.0f - PRE) * mean) * win[i];
        }
        for (int i = FL + lane; i < PW; i += 64) s_fr[lf][i] = 0.f;
    }
    __syncthreads();
    {
        const int bin = tid;
        const float4* dr4 = (const float4*)(dftr + (size_t)bin * PW);
        const float4* di4 = (const float4*)(dfti + (size_t)bin * PW);
        float accr[TFB], acci[TFB];
        #pragma unroll
        for (int f = 0; f < TFB; ++f) { accr[f] = 0.f; acci[f] = 0.f; }
        for (int k4 = 0; k4 < PW / 4; ++k4) {
            const float4 r = dr4[k4], im = di4[k4];
            #pragma unroll
            for (int f = 0; f < TFB; ++f) {
                const float4 fr = *(const float4*)&s_fr[f][k4 * 4];
                accr[f] += fr.x * r.x + fr.y * r.y + fr.z * r.z + fr.w * r.w;
                acci[f] += fr.x * im.x + fr.y * im.y + fr.z * im.z + fr.w * im.w;
            }
        }
        #pragma unroll
        for (int f = 0; f < TFB; ++f) s_pw[f][bin] = accr[f] * accr[f] + acci[f] * acci[f];
    }
    __syncthreads();
    for (int o = tid; o < TFB * NM; o += 256) {
        const int f = o / NM, m = o - f * NM;
        const float* wm = melw + (size_t)m * 257;
        float acc = 0.f;
        for (int k = 0; k < NB; ++k) acc += s_pw[f][k] * wm[k];
        out[(size_t)(fbase + f) * NM + m] = logf(fmaxf(acc + EPSF, EPSF));
    }
}

extern "C" void kernel_launch(void* const* d_in, const int* in_sizes, int n_in,
                              void* d_out, int out_size, void* d_ws, size_t ws_size,
                              hipStream_t stream) {
    const float* wave = (const float*)d_in[0];
    const float* win  = (const float*)d_in[1];
    const float* dftr = (const float*)d_in[2];
    const float* dfti = (const float*)d_in[3];
    const float* melw = (const float*)d_in[4];
    float* out = (float*)d_out;

    if (ws_size >= WS_NEED) {
        u16* wsb = (u16*)d_ws;
        const int prep_threads = 16 * RE_KS * 64 + 16 * IM_KS * 64 + 6 * 8 * 64;  // 20480
        prep_kernel<<<(prep_threads + 255) / 256, 256, 0, stream>>>(dftr, dfti, melw, wsb);
        dim3 grid(NTILES, BATCH);
        fbank_mfma<<<grid, 256, 0, stream>>>(wave, win, wsb, out);
    } else {
        const int nblocks = (BATCH * NFRAMES) / TFB;
        fbank_fallback<<<nblocks, 256, 0, stream>>>(wave, win, dftr, dfti, melw, out);
    }
}